// Round 11
// baseline (475.342 us; speedup 1.0000x reference)
//
#include <hip/hip_runtime.h>
#include <type_traits>

typedef __bf16 bf16x8 __attribute__((ext_vector_type(8)));
typedef __bf16 bf16x4v __attribute__((ext_vector_type(4)));
typedef float f32x4 __attribute__((ext_vector_type(4)));
typedef unsigned short u16x8 __attribute__((ext_vector_type(8)));
typedef unsigned short u16x4 __attribute__((ext_vector_type(4)));

#define NSEQ 4096
#define DM 1024
#define NBATCH 4

__device__ __forceinline__ unsigned short f2bf(float f) {
  unsigned u = __float_as_uint(f);
  u += 0x7FFFu + ((u >> 16) & 1u);
  return (unsigned short)(u >> 16);
}
__device__ __forceinline__ float bf2f(unsigned short h) {
  return __uint_as_float(((unsigned)h) << 16);
}
// branch-free tanh-approx gelu: x * sigmoid(1.5957691*(x + 0.044715 x^3)).
// |err| vs exact erf-gelu < ~1e-3 -> <0.003 absmax after project GEMM.
__device__ __forceinline__ float gelu_fast(float x) {
  const float y = 1.5957691216057308f * (x + 0.044715f * x * x * x);
  return x / (1.0f + __expf(-y));
}

// async global->LDS, 16B per lane; lds dst is wave-uniform base + lane*16
__device__ __forceinline__ void gload_lds16(const unsigned short* src,
                                            unsigned short* dst) {
  __builtin_amdgcn_global_load_lds(
      (const __attribute__((address_space(1))) unsigned int*)src,
      (__attribute__((address_space(3))) unsigned int*)dst, 16, 0, 0);
}

#define BAR() asm volatile("s_barrier" ::: "memory")
#define VMCNT8() asm volatile("s_waitcnt vmcnt(8)" ::: "memory")

// column permutation for expandT': qk cols 0..255 identity; lin (256..2303) and
// pg (2304..4351) paired into 64-col blocks [lin 32 | pg 32].
__device__ __forceinline__ int perm_col(int n) {
  if (n < 256) return n;
  int c = n - 256;
  if (c < 2048) return 256 + ((c >> 5) << 6) + (c & 31);
  c -= 2048;
  return 256 + ((c >> 5) << 6) + 32 + (c & 31);
}

// ---------------- LayerNorm: x (f32) -> nx (bf16) ----------------
__global__ __launch_bounds__(256) void ln_kernel(const float* __restrict__ x,
                                                 unsigned short* __restrict__ nx) {
  const int row = blockIdx.x;
  const int tid = threadIdx.x;
  const float4 v = reinterpret_cast<const float4*>(x + (size_t)row * DM)[tid];
  float s = v.x + v.y + v.z + v.w;
  float q = v.x * v.x + v.y * v.y + v.z * v.z + v.w * v.w;
#pragma unroll
  for (int off = 32; off > 0; off >>= 1) {
    s += __shfl_down(s, off);
    q += __shfl_down(q, off);
  }
  __shared__ float ss[4], sq[4];
  if ((tid & 63) == 0) {
    ss[tid >> 6] = s;
    sq[tid >> 6] = q;
  }
  __syncthreads();
  const float ts = ss[0] + ss[1] + ss[2] + ss[3];
  const float tq = sq[0] + sq[1] + sq[2] + sq[3];
  const float mu = ts * (1.0f / DM);
  const float var = tq * (1.0f / DM) - mu * mu;
  const float rs = rsqrtf(var + 1e-5f);
  u16x4 o;
  o[0] = f2bf((v.x - mu) * rs);
  o[1] = f2bf((v.y - mu) * rs);
  o[2] = f2bf((v.z - mu) * rs);
  o[3] = f2bf((v.w - mu) * rs);
  *reinterpret_cast<u16x4*>(nx + (size_t)row * DM + tid * 4) = o;
}

// ------- transpose+convert: in f32 [K][N] -> out bf16 [N][K], optional perm ------
template <bool PERM>
__global__ __launch_bounds__(256) void tconv_kernel(const float* __restrict__ in,
                                                    unsigned short* __restrict__ out,
                                                    int K, int N) {
  __shared__ unsigned short tile[64][72];
  const int n0 = blockIdx.x * 64;
  const int k0 = blockIdx.y * 64;
  const int tid = threadIdx.x;
  const int lr = tid >> 4, lc = (tid & 15) * 4;
#pragma unroll
  for (int p = 0; p < 4; p++) {
    const int r = lr + p * 16;
    float4 v = *reinterpret_cast<const float4*>(in + (size_t)(k0 + r) * N + n0 + lc);
    tile[r][lc + 0] = f2bf(v.x);
    tile[r][lc + 1] = f2bf(v.y);
    tile[r][lc + 2] = f2bf(v.z);
    tile[r][lc + 3] = f2bf(v.w);
  }
  __syncthreads();
  const int nn = tid >> 2, kkg = (tid & 3) * 16;
  u16x8 o0, o1;
#pragma unroll
  for (int j = 0; j < 8; j++) {
    o0[j] = tile[kkg + j][nn];
    o1[j] = tile[kkg + 8 + j][nn];
  }
  const int orow = PERM ? perm_col(n0 + nn) : (n0 + nn);
  unsigned short* dst = out + (size_t)orow * K + k0 + kkg;
  *reinterpret_cast<u16x8*>(dst) = o0;
  *reinterpret_cast<u16x8*>(dst + 8) = o1;
}

// ---------------- 256x256 8-phase GEMM: C[M,N] = A[M,K] @ Bt[N,K] (bf16) ----------
// Round-8 schedule (best measured): phase = [ds_reads; stage; (vmcnt); BAR; MFMA; BAR].
// MODE 1: f32 out = X + A@Bt^T.
// MODE 2: fused expand epilogue over permuted expandT' (ntn=17):
//   n-tile 0   -> raw bf16 store to qk[16384][256]
//   n-tile >=1 -> gated: acc[I][0..1]=lin, acc[I][2..3]=pg of same cols;
//                 lin*gelu(pg) -> concat (c<1024) or vbuf (c>=1024)
template <int MODE>
__global__ __launch_bounds__(512, 2) void gemm256_kernel(
    const unsigned short* __restrict__ A, int lda,
    const unsigned short* __restrict__ Bt, int ldb, void* __restrict__ Cv,
    void* __restrict__ Cv2, void* __restrict__ Cv3, int ldc, int K, int ntn,
    const float* __restrict__ X) {
  __shared__ unsigned short Ah[2][2][8192];  // [dbuf][khalf][row*32+k]
  __shared__ unsigned short Bh[2][2][8192];
  const int tid = threadIdx.x;
  const int lane = tid & 63;
  const int w = tid >> 6;
  const int lq = lane & 15;
  const int lg = lane >> 4;
  const int wm = w >> 2;  // 0..1
  const int wn = w & 3;   // 0..3
  const int bid = blockIdx.x;
  const int m0 = (bid / ntn) * 256;
  const int n0 = (bid % ntn) * 256;
  const int nk = K >> 6;

  const int g0 = w * 64 + lane;
  const int rowS = g0 >> 2;
  const int kcS = ((g0 & 3) * 8) ^ (((rowS >> 1) & 3) << 3);
  const unsigned short* Asrc = A + (size_t)(m0 + rowS) * lda + kcS;
  const unsigned short* Bsrc = Bt + (size_t)(n0 + rowS) * ldb + kcS;
  const size_t ldaj = (size_t)128 * lda;
  const size_t ldbj = (size_t)128 * ldb;
  const int dstW = w * 64 * 8;

  auto stageA = [&](int db, int kh, int kt2) {
    if (kt2 < nk) {
      const unsigned short* s = Asrc + (size_t)kt2 * 64 + kh * 32;
      unsigned short* d = &Ah[db][kh][0] + dstW;
      gload_lds16(s, d);
      gload_lds16(s + ldaj, d + 4096);
    }
  };
  auto stageB = [&](int db, int kh, int kt2) {
    if (kt2 < nk) {
      const unsigned short* s = Bsrc + (size_t)kt2 * 64 + kh * 32;
      unsigned short* d = &Bh[db][kh][0] + dstW;
      gload_lds16(s, d);
      gload_lds16(s + ldbj, d + 4096);
    }
  };

  f32x4 acc[8][4];
#pragma unroll
  for (int i = 0; i < 8; i++)
#pragma unroll
    for (int j = 0; j < 4; j++)
#pragma unroll
      for (int r = 0; r < 4; r++) acc[i][j][r] = 0.0f;

  stageA(0, 0, 0);
  stageB(0, 0, 0);
  stageA(0, 1, 0);
  stageB(0, 1, 0);
  stageA(1, 0, 1);
  stageB(1, 0, 1);
  VMCNT8();
  BAR();

  const int aBase = wm * 128;
  const int bBase = wn * 64;
  const int cSwz = (lg * 8) ^ (((lq >> 1) & 3) << 3);

#pragma unroll 1
  for (int kt = 0; kt < nk; ++kt) {
    const int buf = kt & 1;
    bf16x8 af[4], bf0[4], bf1[4];

    // ---- phase 0: kh0, rows 0-63; stage A-kh1(kt+1)
#pragma unroll
    for (int i = 0; i < 4; i++)
      af[i] = *reinterpret_cast<const bf16x8*>(
          &Ah[buf][0][(aBase + i * 16 + lq) * 32 + cSwz]);
#pragma unroll
    for (int j = 0; j < 4; j++)
      bf0[j] = *reinterpret_cast<const bf16x8*>(
          &Bh[buf][0][(bBase + j * 16 + lq) * 32 + cSwz]);
    stageA(buf ^ 1, 1, kt + 1);
    BAR();
    __builtin_amdgcn_s_setprio(1);
#pragma unroll
    for (int i = 0; i < 4; i++)
#pragma unroll
      for (int j = 0; j < 4; j++)
        acc[i][j] =
            __builtin_amdgcn_mfma_f32_16x16x32_bf16(af[i], bf0[j], acc[i][j], 0, 0, 0);
    __builtin_amdgcn_s_setprio(0);
    BAR();

    // ---- phase 1: kh0, rows 64-127; stage B-kh1(kt+1); vmcnt(8)
#pragma unroll
    for (int i = 0; i < 4; i++)
      af[i] = *reinterpret_cast<const bf16x8*>(
          &Ah[buf][0][(aBase + 64 + i * 16 + lq) * 32 + cSwz]);
    stageB(buf ^ 1, 1, kt + 1);
    VMCNT8();
    BAR();
    __builtin_amdgcn_s_setprio(1);
#pragma unroll
    for (int i = 0; i < 4; i++)
#pragma unroll
      for (int j = 0; j < 4; j++)
        acc[4 + i][j] = __builtin_amdgcn_mfma_f32_16x16x32_bf16(af[i], bf0[j],
                                                                acc[4 + i][j], 0, 0, 0);
    __builtin_amdgcn_s_setprio(0);
    BAR();

    // ---- phase 2: kh1, rows 0-63; stage A-kh0(kt+2)
#pragma unroll
    for (int i = 0; i < 4; i++)
      af[i] = *reinterpret_cast<const bf16x8*>(
          &Ah[buf][1][(aBase + i * 16 + lq) * 32 + cSwz]);
#pragma unroll
    for (int j = 0; j < 4; j++)
      bf1[j] = *reinterpret_cast<const bf16x8*>(
          &Bh[buf][1][(bBase + j * 16 + lq) * 32 + cSwz]);
    stageA(buf, 0, kt + 2);
    BAR();
    __builtin_amdgcn_s_setprio(1);
#pragma unroll
    for (int i = 0; i < 4; i++)
#pragma unroll
      for (int j = 0; j < 4; j++)
        acc[i][j] =
            __builtin_amdgcn_mfma_f32_16x16x32_bf16(af[i], bf1[j], acc[i][j], 0, 0, 0);
    __builtin_amdgcn_s_setprio(0);
    BAR();

    // ---- phase 3: kh1, rows 64-127; stage B-kh0(kt+2); vmcnt(8)
#pragma unroll
    for (int i = 0; i < 4; i++)
      af[i] = *reinterpret_cast<const bf16x8*>(
          &Ah[buf][1][(aBase + 64 + i * 16 + lq) * 32 + cSwz]);
    stageB(buf, 0, kt + 2);
    VMCNT8();
    BAR();
    __builtin_amdgcn_s_setprio(1);
#pragma unroll
    for (int i = 0; i < 4; i++)
#pragma unroll
      for (int j = 0; j < 4; j++)
        acc[4 + i][j] = __builtin_amdgcn_mfma_f32_16x16x32_bf16(af[i], bf1[j],
                                                                acc[4 + i][j], 0, 0, 0);
    __builtin_amdgcn_s_setprio(0);
    BAR();
  }

  if (MODE == 1) {
    float* C = reinterpret_cast<float*>(Cv);
#pragma unroll
    for (int I = 0; I < 8; I++)
#pragma unroll
      for (int j = 0; j < 4; j++)
#pragma unroll
        for (int r = 0; r < 4; r++) {
          const int row = m0 + wm * 128 + I * 16 + lg * 4 + r;
          const int col = n0 + wn * 64 + j * 16 + lq;
          const size_t off = (size_t)row * ldc + col;
          C[off] = X[off] + acc[I][j][r];
        }
  } else {
    // MODE 2
    if (n0 < 256) {
      // qk tile: raw bf16 store (cols 0..255 of expandT' are identity)
      unsigned short* qkp = reinterpret_cast<unsigned short*>(Cv3);
#pragma unroll
      for (int I = 0; I < 8; I++)
#pragma unroll
        for (int j = 0; j < 4; j++)
#pragma unroll
          for (int r = 0; r < 4; r++) {
            const int row = m0 + wm * 128 + I * 16 + lg * 4 + r;
            const int col = wn * 64 + j * 16 + lq;
            qkp[(size_t)row * 256 + col] = f2bf(acc[I][j][r]);
          }
    } else {
      unsigned short* concat = reinterpret_cast<unsigned short*>(Cv);
      unsigned short* vbuf = reinterpret_cast<unsigned short*>(Cv2);
      const int pc = n0 - 256 + wn * 64;  // offset into gate region
      const int cBase = (pc >> 6) * 32;   // gated col base
#pragma unroll
      for (int I = 0; I < 8; I++)
#pragma unroll
        for (int j = 0; j < 2; j++) {
          const int c = cBase + j * 16 + lq;
#pragma unroll
          for (int r = 0; r < 4; r++) {
            const int row = m0 + wm * 128 + I * 16 + lg * 4 + r;
            const float g = acc[I][j][r] * gelu_fast(acc[I][j + 2][r]);
            if (c < 1024)
              concat[(size_t)row * 2048 + c] = f2bf(g);
            else
              vbuf[(size_t)row * 1024 + (c - 1024)] = f2bf(g);
          }
        }
    }
  }
}

// ---------------- v transpose: vbuf[n][1024] -> vT[b][d][n] ----------------
__global__ __launch_bounds__(256) void vt_kernel(
    const unsigned short* __restrict__ vbuf, unsigned short* __restrict__ vT) {
  __shared__ unsigned short tbuf[64][72];
  const int n0 = blockIdx.x * 64;
  const int d0 = blockIdx.y * 64;
  const int b = blockIdx.z;
  const int tid = threadIdx.x;
#pragma unroll
  for (int p = 0; p < 2; p++) {
    const int r = p * 32 + (tid >> 3);
    const int cg = tid & 7;
    u16x8 v = *reinterpret_cast<const u16x8*>(
        vbuf + (size_t)(b * NSEQ + n0 + r) * 1024 + d0 + cg * 8);
    *reinterpret_cast<u16x8*>(&tbuf[r][cg * 8]) = v;
  }
  __syncthreads();
#pragma unroll
  for (int p = 0; p < 2; p++) {
    const int d = p * 32 + (tid >> 3);
    const int ng = tid & 7;
    u16x8 o;
#pragma unroll
    for (int j = 0; j < 8; j++) o[j] = tbuf[ng * 8 + j][d];
    *reinterpret_cast<u16x8*>(vT + (size_t)(b * DM + d0 + d) * NSEQ + n0 +
                              ng * 8) = o;
  }
}

// ---------------- P kernel: one causal 128x128 tile per block --------------------
#define P_TILE 16384           // 128*128
#define P_PER_B 8650752        // 528 tiles * 16384
__global__ __launch_bounds__(512, 4) void pk_kernel(
    const unsigned short* __restrict__ qk, const float* __restrict__ pbm_ptr,
    unsigned short* __restrict__ P, float* __restrict__ l) {
  __shared__ unsigned short Ks[128][136];
  const int tid = threadIdx.x;
  const int lane = tid & 63;
  const int w = tid >> 6;
  const int lq = lane & 15;
  const int lg = lane >> 4;
  const int bid = blockIdx.x;
  const int b = bid / 528;
  const int t = bid - b * 528;
  int qt = (int)((sqrtf((float)(8 * t + 1)) - 1.0f) * 0.5f);
  while ((qt + 1) * (qt + 2) / 2 <= t) ++qt;
  while (qt * (qt + 1) / 2 > t) --qt;
  const int kt = t - qt * (qt + 1) / 2;
  const float pbm = *pbm_ptr;
  const float SCALE = 0.08838834764831845f;

  const unsigned short* qb = qk + (size_t)b * NSEQ * 256;

#pragma unroll
  for (int p = 0; p < 4; p++) {
    const int task = tid + p * 512;
    const int row = task >> 4;
    const int ch = task & 15;
    bf16x8 v = *reinterpret_cast<const bf16x8*>(
        qb + (size_t)(kt * 128 + row) * 256 + 128 + ch * 8);
    *reinterpret_cast<bf16x8*>(&Ks[row][ch * 8]) = v;
  }
  const int qloc = w * 16 + lq;
  bf16x8 qf[4];
#pragma unroll
  for (int ks = 0; ks < 4; ks++)
    qf[ks] = *reinterpret_cast<const bf16x8*>(
        qb + (size_t)(qt * 128 + qloc) * 256 + ks * 32 + lg * 8);
  __syncthreads();

  f32x4 sa[8];
#pragma unroll
  for (int sub = 0; sub < 8; sub++)
#pragma unroll
    for (int r = 0; r < 4; r++) sa[sub][r] = 0.0f;
#pragma unroll
  for (int ks = 0; ks < 4; ks++)
#pragma unroll
    for (int sub = 0; sub < 8; sub++) {
      bf16x8 kf =
          *reinterpret_cast<const bf16x8*>(&Ks[sub * 16 + lq][ks * 32 + lg * 8]);
      sa[sub] = __builtin_amdgcn_mfma_f32_16x16x32_bf16(kf, qf[ks], sa[sub], 0, 0, 0);
    }
  const size_t KL = (size_t)(qt + 1) * 128;
  unsigned short* Prow = P + (size_t)b * P_PER_B +
                         (size_t)(qt * (qt + 1) / 2) * P_TILE + (size_t)qloc * KL +
                         kt * 128;
  float ps = 0.0f;
  const bool diag = (kt == qt);
#pragma unroll
  for (int sub = 0; sub < 8; sub++) {
    bf16x4v pv;
#pragma unroll
    for (int r = 0; r < 4; r++) {
      const int kvloc = sub * 16 + lg * 4 + r;
      float p;
      if (diag && kvloc > qloc) {
        p = 0.0f;
      } else {
        const float dn = (float)((kt - qt) * 128 + kvloc - qloc) + pbm;
        const float s = sa[sub][r] * SCALE + 1.0f / (1.0f + __expf(-dn));
        p = __expf(s);
      }
      ps += p;
      pv[r] = (__bf16)p;
    }
    *reinterpret_cast<bf16x4v*>(Prow + sub * 16 + lg * 4) = pv;
  }
  ps += __shfl_xor(ps, 16);
  ps += __shfl_xor(ps, 32);
  if (lane < 16) atomicAdd(&l[b * NSEQ + qt * 128 + w * 16 + lane], ps);
}

// ---------------- PV kernel: O[128, 128] = P[128, KL] @ vT^T, /l, -> concat ------
__global__ __launch_bounds__(256, 4) void pv_kernel(
    const unsigned short* __restrict__ P, const unsigned short* __restrict__ vT,
    const float* __restrict__ l, unsigned short* __restrict__ concat) {
  __shared__ unsigned short As[128][64];
  __shared__ unsigned short Bs[128][64];
  const int tid = threadIdx.x;
  const int bid = blockIdx.x;
  const int qt = 31 - (bid >> 5);
  const int rest = bid & 31;
  const int b = rest >> 3;
  const int nt = rest & 7;
  const int KL = (qt + 1) * 128;
  const unsigned short* A =
      P + (size_t)b * P_PER_B + (size_t)(qt * (qt + 1) / 2) * P_TILE;
  const unsigned short* Bt = vT + (size_t)b * DM * NSEQ;
  const int n0 = nt * 128;
  const int lane = tid & 63;
  const int w = tid >> 6;
  const int lr = lane & 15;
  const int lg = lane >> 4;
  const int wr = (w >> 1) * 64;
  const int wc = (w & 1) * 64;
  const int rSwz = (lr & 7) << 3;

  f32x4 acc[4][4];
#pragma unroll
  for (int i = 0; i < 4; i++)
#pragma unroll
    for (int j = 0; j < 4; j++)
#pragma unroll
      for (int r = 0; r < 4; r++) acc[i][j][r] = 0.0f;

  for (int k0 = 0; k0 < KL; k0 += 64) {
#pragma unroll
    for (int j = 0; j < 4; j++) {
      const int boff = w * 4096 + j * 1024 + lane * 16;
      const int row = boff >> 7;
      const int col = (((boff & 127) >> 1)) ^ ((row & 7) << 3);
      gload_lds16(A + (size_t)row * KL + k0 + col,
                  &As[0][0] + (boff - lane * 16) / 2);
    }
#pragma unroll
    for (int j = 0; j < 4; j++) {
      const int boff = w * 4096 + j * 1024 + lane * 16;
      const int row = boff >> 7;
      const int col = (((boff & 127) >> 1)) ^ ((row & 7) << 3);
      gload_lds16(Bt + (size_t)(n0 + row) * NSEQ + k0 + col,
                  &Bs[0][0] + (boff - lane * 16) / 2);
    }
    __syncthreads();
#pragma unroll
    for (int kk = 0; kk < 64; kk += 32) {
      bf16x8 af[4], bfr[4];
#pragma unroll
      for (int i = 0; i < 4; i++)
        af[i] = *reinterpret_cast<const bf16x8*>(
            &As[wr + i * 16 + lr][(kk + lg * 8) ^ rSwz]);
#pragma unroll
      for (int j = 0; j < 4; j++)
        bfr[j] = *reinterpret_cast<const bf16x8*>(
            &Bs[wc + j * 16 + lr][(kk + lg * 8) ^ rSwz]);
#pragma unroll
      for (int i = 0; i < 4; i++)
#pragma unroll
        for (int j = 0; j < 4; j++)
          acc[i][j] = __builtin_amdgcn_mfma_f32_16x16x32_bf16(af[i], bfr[j],
                                                              acc[i][j], 0, 0, 0);
    }
    __syncthreads();
  }

  const float* lb = l + b * NSEQ + qt * 128;
#pragma unroll
  for (int i = 0; i < 4; i++) {
    f32x4 lv = *reinterpret_cast<const f32x4*>(&lb[wr + i * 16 + lg * 4]);
    f32x4 inv;
#pragma unroll
    for (int r = 0; r < 4; r++) inv[r] = 1.0f / lv[r];
#pragma unroll
    for (int j = 0; j < 4; j++)
#pragma unroll
      for (int r = 0; r < 4; r++) {
        const int grow = b * NSEQ + qt * 128 + wr + i * 16 + lg * 4 + r;
        const int col = 1024 + n0 + wc + j * 16 + lr;
        concat[(size_t)grow * 2048 + col] = f2bf(acc[i][j][r] * inv[r]);
      }
  }
}

extern "C" void kernel_launch(void* const* d_in, const int* in_sizes, int n_in,
                              void* d_out, int out_size, void* d_ws,
                              size_t ws_size, hipStream_t stream) {
  (void)in_sizes;
  (void)n_in;
  (void)out_size;
  const float* x = (const float*)d_in[0];
  const float* expand = (const float*)d_in[1];
  const float* project = (const float*)d_in[2];
  const float* pbm = (const float*)d_in[3];
  float* out = (float*)d_out;

  const size_t QK_BYTES = (size_t)16384 * 256 * 2;
  const size_t VBUF_BYTES = (size_t)16384 * 1024 * 2;
  const size_t P_BYTES = (size_t)NBATCH * P_PER_B * 2;
  const size_t L_BYTES = (size_t)NBATCH * NSEQ * 4;
  const size_t GH_BYTES = (size_t)16384 * 4096 * 2;
  const size_t CAT_BYTES = (size_t)16384 * 2048 * 2;
  const size_t NX_BYTES = (size_t)16384 * DM * 2;
  if (ws_size < QK_BYTES + GH_BYTES + CAT_BYTES + NX_BYTES) return;

  char* ws = (char*)d_ws;
  unsigned short* qk = (unsigned short*)ws;
  unsigned short* vbuf = (unsigned short*)(ws + QK_BYTES);
  unsigned short* P = (unsigned short*)(ws + QK_BYTES + VBUF_BYTES);
  float* l = (float*)(ws + QK_BYTES + VBUF_BYTES + P_BYTES);
  unsigned short* expandT =
      (unsigned short*)(ws + QK_BYTES + VBUF_BYTES + P_BYTES + L_BYTES);
  unsigned short* concat = (unsigned short*)(ws + QK_BYTES + GH_BYTES);
  unsigned short* nx = (unsigned short*)(ws + QK_BYTES + GH_BYTES + CAT_BYTES);
  unsigned short* vT = nx;
  unsigned short* projectT = nx;

  // 0a. expandT'[perm(n)][k] = bf16(expand[k][n])
  tconv_kernel<true><<<dim3(68, 16), 256, 0, stream>>>(expand, expandT, 1024, 4352);
  // 1. LayerNorm
  ln_kernel<<<16384, 256, 0, stream>>>(x, nx);
  // 2. fused expand GEMM over all 4352 cols: qk + local->concat + v->vbuf
  gemm256_kernel<2><<<dim3(64 * 17), 512, 0, stream>>>(
      nx, DM, expandT, DM, (void*)concat, (void*)vbuf, (void*)qk, 0, DM, 17,
      nullptr);
  // 3. v transpose (nx dead; vT overwrites it)
  vt_kernel<<<dim3(64, 16, 4), 256, 0, stream>>>(vbuf, vT);
  // 4. P = softmax numerator; l zeroed first
  hipMemsetAsync(l, 0, L_BYTES, stream);
  pk_kernel<<<dim3(NBATCH * 528), 512, 0, stream>>>(qk, pbm, P, l);
  // 5. attn = (P @ V) / l -> concat[:, 1024:2048]
  pv_kernel<<<dim3(1024), 256, 0, stream>>>(P, vT, l, concat);
  // 6. projectT (vT dead)
  tconv_kernel<false><<<dim3(16, 32), 256, 0, stream>>>(project, projectT, 2048, DM);
  // 7. out = x + concat @ projectT^T
  gemm256_kernel<1><<<dim3(64 * 4), 512, 0, stream>>>(
      concat, 2048, projectT, 2048, (void*)out, nullptr, nullptr, DM, 2048, 4, x);
}

// Round 12
// 453.211 us; speedup vs baseline: 1.0488x; 1.0488x over previous
//
#include <hip/hip_runtime.h>
#include <type_traits>

typedef __bf16 bf16x8 __attribute__((ext_vector_type(8)));
typedef __bf16 bf16x4v __attribute__((ext_vector_type(4)));
typedef float f32x4 __attribute__((ext_vector_type(4)));
typedef unsigned short u16x8 __attribute__((ext_vector_type(8)));
typedef unsigned short u16x4 __attribute__((ext_vector_type(4)));

#define NSEQ 4096
#define DM 1024
#define NBATCH 4

__device__ __forceinline__ unsigned short f2bf(float f) {
  unsigned u = __float_as_uint(f);
  u += 0x7FFFu + ((u >> 16) & 1u);
  return (unsigned short)(u >> 16);
}
__device__ __forceinline__ float bf2f(unsigned short h) {
  return __uint_as_float(((unsigned)h) << 16);
}
// branch-free tanh-approx gelu (round-11, verified absmax 0.03125)
__device__ __forceinline__ float gelu_fast(float x) {
  const float y = 1.5957691216057308f * (x + 0.044715f * x * x * x);
  return x / (1.0f + __expf(-y));
}

// async global->LDS, 16B per lane; lds dst is wave-uniform base + lane*16
__device__ __forceinline__ void gload_lds16(const unsigned short* src,
                                            unsigned short* dst) {
  __builtin_amdgcn_global_load_lds(
      (const __attribute__((address_space(1))) unsigned int*)src,
      (__attribute__((address_space(3))) unsigned int*)dst, 16, 0, 0);
}

#define BAR() asm volatile("s_barrier" ::: "memory")
#define VMCNT8() asm volatile("s_waitcnt vmcnt(8)" ::: "memory")

// column permutation for expandT': qk cols 0..255 identity; lin (256..2303) and
// pg (2304..4351) paired into 64-col blocks [lin 32 | pg 32].
__device__ __forceinline__ int perm_col(int n) {
  if (n < 256) return n;
  int c = n - 256;
  if (c < 2048) return 256 + ((c >> 5) << 6) + (c & 31);
  c -= 2048;
  return 256 + ((c >> 5) << 6) + 32 + (c & 31);
}

// ---------------- LayerNorm: x (f32) -> nx (bf16) ----------------
__global__ __launch_bounds__(256) void ln_kernel(const float* __restrict__ x,
                                                 unsigned short* __restrict__ nx) {
  const int row = blockIdx.x;
  const int tid = threadIdx.x;
  const float4 v = reinterpret_cast<const float4*>(x + (size_t)row * DM)[tid];
  float s = v.x + v.y + v.z + v.w;
  float q = v.x * v.x + v.y * v.y + v.z * v.z + v.w * v.w;
#pragma unroll
  for (int off = 32; off > 0; off >>= 1) {
    s += __shfl_down(s, off);
    q += __shfl_down(q, off);
  }
  __shared__ float ss[4], sq[4];
  if ((tid & 63) == 0) {
    ss[tid >> 6] = s;
    sq[tid >> 6] = q;
  }
  __syncthreads();
  const float ts = ss[0] + ss[1] + ss[2] + ss[3];
  const float tq = sq[0] + sq[1] + sq[2] + sq[3];
  const float mu = ts * (1.0f / DM);
  const float var = tq * (1.0f / DM) - mu * mu;
  const float rs = rsqrtf(var + 1e-5f);
  u16x4 o;
  o[0] = f2bf((v.x - mu) * rs);
  o[1] = f2bf((v.y - mu) * rs);
  o[2] = f2bf((v.z - mu) * rs);
  o[3] = f2bf((v.w - mu) * rs);
  *reinterpret_cast<u16x4*>(nx + (size_t)row * DM + tid * 4) = o;
}

// ------- transpose+convert: in f32 [K][N] -> out bf16 [N][K], optional perm ------
template <bool PERM>
__global__ __launch_bounds__(256) void tconv_kernel(const float* __restrict__ in,
                                                    unsigned short* __restrict__ out,
                                                    int K, int N) {
  __shared__ unsigned short tile[64][72];
  const int n0 = blockIdx.x * 64;
  const int k0 = blockIdx.y * 64;
  const int tid = threadIdx.x;
  const int lr = tid >> 4, lc = (tid & 15) * 4;
#pragma unroll
  for (int p = 0; p < 4; p++) {
    const int r = lr + p * 16;
    float4 v = *reinterpret_cast<const float4*>(in + (size_t)(k0 + r) * N + n0 + lc);
    tile[r][lc + 0] = f2bf(v.x);
    tile[r][lc + 1] = f2bf(v.y);
    tile[r][lc + 2] = f2bf(v.z);
    tile[r][lc + 3] = f2bf(v.w);
  }
  __syncthreads();
  const int nn = tid >> 2, kkg = (tid & 3) * 16;
  u16x8 o0, o1;
#pragma unroll
  for (int j = 0; j < 8; j++) {
    o0[j] = tile[kkg + j][nn];
    o1[j] = tile[kkg + 8 + j][nn];
  }
  const int orow = PERM ? perm_col(n0 + nn) : (n0 + nn);
  unsigned short* dst = out + (size_t)orow * K + k0 + kkg;
  *reinterpret_cast<u16x8*>(dst) = o0;
  *reinterpret_cast<u16x8*>(dst + 8) = o1;
}

// ---------------- 256x256 8-phase GEMM: C[M,N] = A[M,K] @ Bt[N,K] (bf16) ----------
// Round-8 schedule: phase = [ds_reads; stage; (vmcnt); BAR; MFMA; BAR].
// MODE 1: f32 out = X + A@Bt^T.
// MODE 2: gated epilogue (Bt = permuted gate region, ntn=16): acc[I][0..1]=lin,
//         acc[I][2..3]=pg of same cols; lin*gelu_fast(pg) -> concat / vbuf.
template <int MODE>
__global__ __launch_bounds__(512, 2) void gemm256_kernel(
    const unsigned short* __restrict__ A, int lda,
    const unsigned short* __restrict__ Bt, int ldb, void* __restrict__ Cv,
    void* __restrict__ Cv2, int ldc, int K, int ntn,
    const float* __restrict__ X) {
  __shared__ unsigned short Ah[2][2][8192];  // [dbuf][khalf][row*32+k]
  __shared__ unsigned short Bh[2][2][8192];
  const int tid = threadIdx.x;
  const int lane = tid & 63;
  const int w = tid >> 6;
  const int lq = lane & 15;
  const int lg = lane >> 4;
  const int wm = w >> 2;  // 0..1
  const int wn = w & 3;   // 0..3
  const int bid = blockIdx.x;
  const int m0 = (bid / ntn) * 256;
  const int n0 = (bid % ntn) * 256;
  const int nk = K >> 6;

  const int g0 = w * 64 + lane;
  const int rowS = g0 >> 2;
  const int kcS = ((g0 & 3) * 8) ^ (((rowS >> 1) & 3) << 3);
  const unsigned short* Asrc = A + (size_t)(m0 + rowS) * lda + kcS;
  const unsigned short* Bsrc = Bt + (size_t)(n0 + rowS) * ldb + kcS;
  const size_t ldaj = (size_t)128 * lda;
  const size_t ldbj = (size_t)128 * ldb;
  const int dstW = w * 64 * 8;

  auto stageA = [&](int db, int kh, int kt2) {
    if (kt2 < nk) {
      const unsigned short* s = Asrc + (size_t)kt2 * 64 + kh * 32;
      unsigned short* d = &Ah[db][kh][0] + dstW;
      gload_lds16(s, d);
      gload_lds16(s + ldaj, d + 4096);
    }
  };
  auto stageB = [&](int db, int kh, int kt2) {
    if (kt2 < nk) {
      const unsigned short* s = Bsrc + (size_t)kt2 * 64 + kh * 32;
      unsigned short* d = &Bh[db][kh][0] + dstW;
      gload_lds16(s, d);
      gload_lds16(s + ldbj, d + 4096);
    }
  };

  f32x4 acc[8][4];
#pragma unroll
  for (int i = 0; i < 8; i++)
#pragma unroll
    for (int j = 0; j < 4; j++)
#pragma unroll
      for (int r = 0; r < 4; r++) acc[i][j][r] = 0.0f;

  stageA(0, 0, 0);
  stageB(0, 0, 0);
  stageA(0, 1, 0);
  stageB(0, 1, 0);
  stageA(1, 0, 1);
  stageB(1, 0, 1);
  VMCNT8();
  BAR();

  const int aBase = wm * 128;
  const int bBase = wn * 64;
  const int cSwz = (lg * 8) ^ (((lq >> 1) & 3) << 3);

#pragma unroll 1
  for (int kt = 0; kt < nk; ++kt) {
    const int buf = kt & 1;
    bf16x8 af[4], bf0[4], bf1[4];

    // ---- phase 0: kh0, rows 0-63; stage A-kh1(kt+1)
#pragma unroll
    for (int i = 0; i < 4; i++)
      af[i] = *reinterpret_cast<const bf16x8*>(
          &Ah[buf][0][(aBase + i * 16 + lq) * 32 + cSwz]);
#pragma unroll
    for (int j = 0; j < 4; j++)
      bf0[j] = *reinterpret_cast<const bf16x8*>(
          &Bh[buf][0][(bBase + j * 16 + lq) * 32 + cSwz]);
    stageA(buf ^ 1, 1, kt + 1);
    BAR();
    __builtin_amdgcn_s_setprio(1);
#pragma unroll
    for (int i = 0; i < 4; i++)
#pragma unroll
      for (int j = 0; j < 4; j++)
        acc[i][j] =
            __builtin_amdgcn_mfma_f32_16x16x32_bf16(af[i], bf0[j], acc[i][j], 0, 0, 0);
    __builtin_amdgcn_s_setprio(0);
    BAR();

    // ---- phase 1: kh0, rows 64-127; stage B-kh1(kt+1); vmcnt(8)
#pragma unroll
    for (int i = 0; i < 4; i++)
      af[i] = *reinterpret_cast<const bf16x8*>(
          &Ah[buf][0][(aBase + 64 + i * 16 + lq) * 32 + cSwz]);
    stageB(buf ^ 1, 1, kt + 1);
    VMCNT8();
    BAR();
    __builtin_amdgcn_s_setprio(1);
#pragma unroll
    for (int i = 0; i < 4; i++)
#pragma unroll
      for (int j = 0; j < 4; j++)
        acc[4 + i][j] = __builtin_amdgcn_mfma_f32_16x16x32_bf16(af[i], bf0[j],
                                                                acc[4 + i][j], 0, 0, 0);
    __builtin_amdgcn_s_setprio(0);
    BAR();

    // ---- phase 2: kh1, rows 0-63; stage A-kh0(kt+2)
#pragma unroll
    for (int i = 0; i < 4; i++)
      af[i] = *reinterpret_cast<const bf16x8*>(
          &Ah[buf][1][(aBase + i * 16 + lq) * 32 + cSwz]);
#pragma unroll
    for (int j = 0; j < 4; j++)
      bf1[j] = *reinterpret_cast<const bf16x8*>(
          &Bh[buf][1][(bBase + j * 16 + lq) * 32 + cSwz]);
    stageA(buf, 0, kt + 2);
    BAR();
    __builtin_amdgcn_s_setprio(1);
#pragma unroll
    for (int i = 0; i < 4; i++)
#pragma unroll
      for (int j = 0; j < 4; j++)
        acc[i][j] =
            __builtin_amdgcn_mfma_f32_16x16x32_bf16(af[i], bf1[j], acc[i][j], 0, 0, 0);
    __builtin_amdgcn_s_setprio(0);
    BAR();

    // ---- phase 3: kh1, rows 64-127; stage B-kh0(kt+2); vmcnt(8)
#pragma unroll
    for (int i = 0; i < 4; i++)
      af[i] = *reinterpret_cast<const bf16x8*>(
          &Ah[buf][1][(aBase + 64 + i * 16 + lq) * 32 + cSwz]);
    stageB(buf, 0, kt + 2);
    VMCNT8();
    BAR();
    __builtin_amdgcn_s_setprio(1);
#pragma unroll
    for (int i = 0; i < 4; i++)
#pragma unroll
      for (int j = 0; j < 4; j++)
        acc[4 + i][j] = __builtin_amdgcn_mfma_f32_16x16x32_bf16(af[i], bf1[j],
                                                                acc[4 + i][j], 0, 0, 0);
    __builtin_amdgcn_s_setprio(0);
    BAR();
  }

  if (MODE == 1) {
    float* C = reinterpret_cast<float*>(Cv);
#pragma unroll
    for (int I = 0; I < 8; I++)
#pragma unroll
      for (int j = 0; j < 4; j++)
#pragma unroll
        for (int r = 0; r < 4; r++) {
          const int row = m0 + wm * 128 + I * 16 + lg * 4 + r;
          const int col = n0 + wn * 64 + j * 16 + lq;
          const size_t off = (size_t)row * ldc + col;
          C[off] = X[off] + acc[I][j][r];
        }
  } else {
    // MODE 2: gated. physical slice (n0+wn*64) -> gated col base pi*32.
    unsigned short* concat = reinterpret_cast<unsigned short*>(Cv);
    unsigned short* vbuf = reinterpret_cast<unsigned short*>(Cv2);
    const int pi = (n0 + wn * 64) >> 6;
    const int cBase = pi * 32;
#pragma unroll
    for (int I = 0; I < 8; I++)
#pragma unroll
      for (int j = 0; j < 2; j++) {
        const int c = cBase + j * 16 + lq;
#pragma unroll
        for (int r = 0; r < 4; r++) {
          const int row = m0 + wm * 128 + I * 16 + lg * 4 + r;
          const float g = acc[I][j][r] * gelu_fast(acc[I][j + 2][r]);
          if (c < 1024)
            concat[(size_t)row * 2048 + c] = f2bf(g);
          else
            vbuf[(size_t)row * 1024 + (c - 1024)] = f2bf(g);
        }
      }
  }
}

// ---------------- qk kernel: qk[16384][256] = nx @ expandT[0:256]^T -------------
// 128x128-tile m97 structure (pv_kernel schedule), grid = 128 m x 2 n = 256
// blocks -> 1 block/CU chip-wide (fixes the old grid-64 serialization).
__global__ __launch_bounds__(256, 4) void qk_kernel(
    const unsigned short* __restrict__ nx, const unsigned short* __restrict__ eT,
    unsigned short* __restrict__ qk) {
  __shared__ unsigned short As[128][64];
  __shared__ unsigned short Bs[128][64];
  const int tid = threadIdx.x;
  const int m0 = (blockIdx.x >> 1) * 128;
  const int n0 = (blockIdx.x & 1) * 128;
  const int lane = tid & 63;
  const int w = tid >> 6;
  const int lr = lane & 15;
  const int lg = lane >> 4;
  const int wr = (w >> 1) * 64;
  const int wc = (w & 1) * 64;
  const int rSwz = (lr & 7) << 3;

  f32x4 acc[4][4];
#pragma unroll
  for (int i = 0; i < 4; i++)
#pragma unroll
    for (int j = 0; j < 4; j++)
#pragma unroll
      for (int r = 0; r < 4; r++) acc[i][j][r] = 0.0f;

  for (int k0 = 0; k0 < 1024; k0 += 64) {
#pragma unroll
    for (int j = 0; j < 4; j++) {
      const int boff = w * 4096 + j * 1024 + lane * 16;
      const int row = boff >> 7;
      const int col = (((boff & 127) >> 1)) ^ ((row & 7) << 3);
      gload_lds16(nx + (size_t)(m0 + row) * DM + k0 + col,
                  &As[0][0] + (boff - lane * 16) / 2);
    }
#pragma unroll
    for (int j = 0; j < 4; j++) {
      const int boff = w * 4096 + j * 1024 + lane * 16;
      const int row = boff >> 7;
      const int col = (((boff & 127) >> 1)) ^ ((row & 7) << 3);
      gload_lds16(eT + (size_t)(n0 + row) * DM + k0 + col,
                  &Bs[0][0] + (boff - lane * 16) / 2);
    }
    __syncthreads();
#pragma unroll
    for (int kk = 0; kk < 64; kk += 32) {
      bf16x8 af[4], bfr[4];
#pragma unroll
      for (int i = 0; i < 4; i++)
        af[i] = *reinterpret_cast<const bf16x8*>(
            &As[wr + i * 16 + lr][(kk + lg * 8) ^ rSwz]);
#pragma unroll
      for (int j = 0; j < 4; j++)
        bfr[j] = *reinterpret_cast<const bf16x8*>(
            &Bs[wc + j * 16 + lr][(kk + lg * 8) ^ rSwz]);
#pragma unroll
      for (int i = 0; i < 4; i++)
#pragma unroll
        for (int j = 0; j < 4; j++)
          acc[i][j] = __builtin_amdgcn_mfma_f32_16x16x32_bf16(af[i], bfr[j],
                                                              acc[i][j], 0, 0, 0);
    }
    __syncthreads();
  }

#pragma unroll
  for (int i = 0; i < 4; i++)
#pragma unroll
    for (int j = 0; j < 4; j++)
#pragma unroll
      for (int r = 0; r < 4; r++) {
        const int row = m0 + wr + i * 16 + lg * 4 + r;
        const int col = n0 + wc + j * 16 + lr;
        qk[(size_t)row * 256 + col] = f2bf(acc[i][j][r]);
      }
}

// ---------------- v transpose: vbuf[n][1024] -> vT[b][d][n] ----------------
__global__ __launch_bounds__(256) void vt_kernel(
    const unsigned short* __restrict__ vbuf, unsigned short* __restrict__ vT) {
  __shared__ unsigned short tbuf[64][72];
  const int n0 = blockIdx.x * 64;
  const int d0 = blockIdx.y * 64;
  const int b = blockIdx.z;
  const int tid = threadIdx.x;
#pragma unroll
  for (int p = 0; p < 2; p++) {
    const int r = p * 32 + (tid >> 3);
    const int cg = tid & 7;
    u16x8 v = *reinterpret_cast<const u16x8*>(
        vbuf + (size_t)(b * NSEQ + n0 + r) * 1024 + d0 + cg * 8);
    *reinterpret_cast<u16x8*>(&tbuf[r][cg * 8]) = v;
  }
  __syncthreads();
#pragma unroll
  for (int p = 0; p < 2; p++) {
    const int d = p * 32 + (tid >> 3);
    const int ng = tid & 7;
    u16x8 o;
#pragma unroll
    for (int j = 0; j < 8; j++) o[j] = tbuf[ng * 8 + j][d];
    *reinterpret_cast<u16x8*>(vT + (size_t)(b * DM + d0 + d) * NSEQ + n0 +
                              ng * 8) = o;
  }
}

// ---------------- P kernel: one causal 128x128 tile per block --------------------
#define P_TILE 16384           // 128*128
#define P_PER_B 8650752        // 528 tiles * 16384
__global__ __launch_bounds__(512, 4) void pk_kernel(
    const unsigned short* __restrict__ qk, const float* __restrict__ pbm_ptr,
    unsigned short* __restrict__ P, float* __restrict__ l) {
  __shared__ unsigned short Ks[128][136];
  const int tid = threadIdx.x;
  const int lane = tid & 63;
  const int w = tid >> 6;
  const int lq = lane & 15;
  const int lg = lane >> 4;
  const int bid = blockIdx.x;
  const int b = bid / 528;
  const int t = bid - b * 528;
  int qt = (int)((sqrtf((float)(8 * t + 1)) - 1.0f) * 0.5f);
  while ((qt + 1) * (qt + 2) / 2 <= t) ++qt;
  while (qt * (qt + 1) / 2 > t) --qt;
  const int kt = t - qt * (qt + 1) / 2;
  const float pbm = *pbm_ptr;
  const float SCALE = 0.08838834764831845f;

  const unsigned short* qb = qk + (size_t)b * NSEQ * 256;

#pragma unroll
  for (int p = 0; p < 4; p++) {
    const int task = tid + p * 512;
    const int row = task >> 4;
    const int ch = task & 15;
    bf16x8 v = *reinterpret_cast<const bf16x8*>(
        qb + (size_t)(kt * 128 + row) * 256 + 128 + ch * 8);
    *reinterpret_cast<bf16x8*>(&Ks[row][ch * 8]) = v;
  }
  const int qloc = w * 16 + lq;
  bf16x8 qf[4];
#pragma unroll
  for (int ks = 0; ks < 4; ks++)
    qf[ks] = *reinterpret_cast<const bf16x8*>(
        qb + (size_t)(qt * 128 + qloc) * 256 + ks * 32 + lg * 8);
  __syncthreads();

  f32x4 sa[8];
#pragma unroll
  for (int sub = 0; sub < 8; sub++)
#pragma unroll
    for (int r = 0; r < 4; r++) sa[sub][r] = 0.0f;
#pragma unroll
  for (int ks = 0; ks < 4; ks++)
#pragma unroll
    for (int sub = 0; sub < 8; sub++) {
      bf16x8 kf =
          *reinterpret_cast<const bf16x8*>(&Ks[sub * 16 + lq][ks * 32 + lg * 8]);
      sa[sub] = __builtin_amdgcn_mfma_f32_16x16x32_bf16(kf, qf[ks], sa[sub], 0, 0, 0);
    }
  const size_t KL = (size_t)(qt + 1) * 128;
  unsigned short* Prow = P + (size_t)b * P_PER_B +
                         (size_t)(qt * (qt + 1) / 2) * P_TILE + (size_t)qloc * KL +
                         kt * 128;
  float ps = 0.0f;
  const bool diag = (kt == qt);
#pragma unroll
  for (int sub = 0; sub < 8; sub++) {
    bf16x4v pv;
#pragma unroll
    for (int r = 0; r < 4; r++) {
      const int kvloc = sub * 16 + lg * 4 + r;
      float p;
      if (diag && kvloc > qloc) {
        p = 0.0f;
      } else {
        const float dn = (float)((kt - qt) * 128 + kvloc - qloc) + pbm;
        const float s = sa[sub][r] * SCALE + 1.0f / (1.0f + __expf(-dn));
        p = __expf(s);
      }
      ps += p;
      pv[r] = (__bf16)p;
    }
    *reinterpret_cast<bf16x4v*>(Prow + sub * 16 + lg * 4) = pv;
  }
  ps += __shfl_xor(ps, 16);
  ps += __shfl_xor(ps, 32);
  if (lane < 16) atomicAdd(&l[b * NSEQ + qt * 128 + w * 16 + lane], ps);
}

// ---------------- PV kernel: O[128, 128] = P[128, KL] @ vT^T, /l, -> concat ------
__global__ __launch_bounds__(256, 4) void pv_kernel(
    const unsigned short* __restrict__ P, const unsigned short* __restrict__ vT,
    const float* __restrict__ l, unsigned short* __restrict__ concat) {
  __shared__ unsigned short As[128][64];
  __shared__ unsigned short Bs[128][64];
  const int tid = threadIdx.x;
  const int bid = blockIdx.x;
  const int qt = 31 - (bid >> 5);
  const int rest = bid & 31;
  const int b = rest >> 3;
  const int nt = rest & 7;
  const int KL = (qt + 1) * 128;
  const unsigned short* A =
      P + (size_t)b * P_PER_B + (size_t)(qt * (qt + 1) / 2) * P_TILE;
  const unsigned short* Bt = vT + (size_t)b * DM * NSEQ;
  const int n0 = nt * 128;
  const int lane = tid & 63;
  const int w = tid >> 6;
  const int lr = lane & 15;
  const int lg = lane >> 4;
  const int wr = (w >> 1) * 64;
  const int wc = (w & 1) * 64;
  const int rSwz = (lr & 7) << 3;

  f32x4 acc[4][4];
#pragma unroll
  for (int i = 0; i < 4; i++)
#pragma unroll
    for (int j = 0; j < 4; j++)
#pragma unroll
      for (int r = 0; r < 4; r++) acc[i][j][r] = 0.0f;

  for (int k0 = 0; k0 < KL; k0 += 64) {
#pragma unroll
    for (int j = 0; j < 4; j++) {
      const int boff = w * 4096 + j * 1024 + lane * 16;
      const int row = boff >> 7;
      const int col = (((boff & 127) >> 1)) ^ ((row & 7) << 3);
      gload_lds16(A + (size_t)row * KL + k0 + col,
                  &As[0][0] + (boff - lane * 16) / 2);
    }
#pragma unroll
    for (int j = 0; j < 4; j++) {
      const int boff = w * 4096 + j * 1024 + lane * 16;
      const int row = boff >> 7;
      const int col = (((boff & 127) >> 1)) ^ ((row & 7) << 3);
      gload_lds16(Bt + (size_t)(n0 + row) * NSEQ + k0 + col,
                  &Bs[0][0] + (boff - lane * 16) / 2);
    }
    __syncthreads();
#pragma unroll
    for (int kk = 0; kk < 64; kk += 32) {
      bf16x8 af[4], bfr[4];
#pragma unroll
      for (int i = 0; i < 4; i++)
        af[i] = *reinterpret_cast<const bf16x8*>(
            &As[wr + i * 16 + lr][(kk + lg * 8) ^ rSwz]);
#pragma unroll
      for (int j = 0; j < 4; j++)
        bfr[j] = *reinterpret_cast<const bf16x8*>(
            &Bs[wc + j * 16 + lr][(kk + lg * 8) ^ rSwz]);
#pragma unroll
      for (int i = 0; i < 4; i++)
#pragma unroll
        for (int j = 0; j < 4; j++)
          acc[i][j] = __builtin_amdgcn_mfma_f32_16x16x32_bf16(af[i], bfr[j],
                                                              acc[i][j], 0, 0, 0);
    }
    __syncthreads();
  }

  const float* lb = l + b * NSEQ + qt * 128;
#pragma unroll
  for (int i = 0; i < 4; i++) {
    f32x4 lv = *reinterpret_cast<const f32x4*>(&lb[wr + i * 16 + lg * 4]);
    f32x4 inv;
#pragma unroll
    for (int r = 0; r < 4; r++) inv[r] = 1.0f / lv[r];
#pragma unroll
    for (int j = 0; j < 4; j++)
#pragma unroll
      for (int r = 0; r < 4; r++) {
        const int grow = b * NSEQ + qt * 128 + wr + i * 16 + lg * 4 + r;
        const int col = 1024 + n0 + wc + j * 16 + lr;
        concat[(size_t)grow * 2048 + col] = f2bf(acc[i][j][r] * inv[r]);
      }
  }
}

extern "C" void kernel_launch(void* const* d_in, const int* in_sizes, int n_in,
                              void* d_out, int out_size, void* d_ws,
                              size_t ws_size, hipStream_t stream) {
  (void)in_sizes;
  (void)n_in;
  (void)out_size;
  const float* x = (const float*)d_in[0];
  const float* expand = (const float*)d_in[1];
  const float* project = (const float*)d_in[2];
  const float* pbm = (const float*)d_in[3];
  float* out = (float*)d_out;

  const size_t QK_BYTES = (size_t)16384 * 256 * 2;
  const size_t VBUF_BYTES = (size_t)16384 * 1024 * 2;
  const size_t P_BYTES = (size_t)NBATCH * P_PER_B * 2;
  const size_t L_BYTES = (size_t)NBATCH * NSEQ * 4;
  const size_t GH_BYTES = (size_t)16384 * 4096 * 2;
  const size_t CAT_BYTES = (size_t)16384 * 2048 * 2;
  const size_t NX_BYTES = (size_t)16384 * DM * 2;
  if (ws_size < QK_BYTES + GH_BYTES + CAT_BYTES + NX_BYTES) return;

  char* ws = (char*)d_ws;
  unsigned short* qk = (unsigned short*)ws;
  unsigned short* vbuf = (unsigned short*)(ws + QK_BYTES);
  unsigned short* P = (unsigned short*)(ws + QK_BYTES + VBUF_BYTES);
  float* l = (float*)(ws + QK_BYTES + VBUF_BYTES + P_BYTES);
  unsigned short* expandT =
      (unsigned short*)(ws + QK_BYTES + VBUF_BYTES + P_BYTES + L_BYTES);
  unsigned short* concat = (unsigned short*)(ws + QK_BYTES + GH_BYTES);
  unsigned short* nx = (unsigned short*)(ws + QK_BYTES + GH_BYTES + CAT_BYTES);
  unsigned short* vT = nx;
  unsigned short* projectT = nx;

  // 0a. expandT'[perm(n)][k] = bf16(expand[k][n])
  tconv_kernel<true><<<dim3(68, 16), 256, 0, stream>>>(expand, expandT, 1024, 4352);
  // 1. LayerNorm
  ln_kernel<<<16384, 256, 0, stream>>>(x, nx);
  // 2a. qk = nx @ expandT'[0:256]^T  (128-tile, 256 blocks)
  qk_kernel<<<dim3(256), 256, 0, stream>>>(nx, expandT, qk);
  // 2b. gated GEMM (ntn=16): local->concat[:, :1024], v->vbuf
  gemm256_kernel<2><<<dim3(64 * 16), 512, 0, stream>>>(
      nx, DM, expandT + (size_t)256 * DM, DM, (void*)concat, (void*)vbuf, 0, DM,
      16, nullptr);
  // 3. v transpose (nx dead; vT overwrites it)
  vt_kernel<<<dim3(64, 16, 4), 256, 0, stream>>>(vbuf, vT);
  // 4. P = softmax numerator; l zeroed first
  hipMemsetAsync(l, 0, L_BYTES, stream);
  pk_kernel<<<dim3(NBATCH * 528), 512, 0, stream>>>(qk, pbm, P, l);
  // 5. attn = (P @ V) / l -> concat[:, 1024:2048]
  pv_kernel<<<dim3(1024), 256, 0, stream>>>(P, vT, l, concat);
  // 6. projectT (vT dead)
  tconv_kernel<false><<<dim3(16, 32), 256, 0, stream>>>(project, projectT, 2048, DM);
  // 7. out = x + concat @ projectT^T
  gemm256_kernel<1><<<dim3(64 * 4), 512, 0, stream>>>(
      concat, 2048, projectT, 2048, (void*)out, nullptr, DM, 2048, 4, x);
}

// Round 13
// 428.569 us; speedup vs baseline: 1.1091x; 1.0575x over previous
//
#include <hip/hip_runtime.h>
#include <type_traits>

typedef __bf16 bf16x8 __attribute__((ext_vector_type(8)));
typedef __bf16 bf16x4v __attribute__((ext_vector_type(4)));
typedef float f32x4 __attribute__((ext_vector_type(4)));
typedef unsigned short u16x8 __attribute__((ext_vector_type(8)));
typedef unsigned short u16x4 __attribute__((ext_vector_type(4)));

#define NSEQ 4096
#define DM 1024
#define NBATCH 4

__device__ __forceinline__ unsigned short f2bf(float f) {
  unsigned u = __float_as_uint(f);
  u += 0x7FFFu + ((u >> 16) & 1u);
  return (unsigned short)(u >> 16);
}
__device__ __forceinline__ float bf2f(unsigned short h) {
  return __uint_as_float(((unsigned)h) << 16);
}
// branch-free tanh-approx gelu (round-11, verified absmax 0.03125)
__device__ __forceinline__ float gelu_fast(float x) {
  const float y = 1.5957691216057308f * (x + 0.044715f * x * x * x);
  return x / (1.0f + __expf(-y));
}

// async global->LDS, 16B per lane; lds dst is wave-uniform base + lane*16
__device__ __forceinline__ void gload_lds16(const unsigned short* src,
                                            unsigned short* dst) {
  __builtin_amdgcn_global_load_lds(
      (const __attribute__((address_space(1))) unsigned int*)src,
      (__attribute__((address_space(3))) unsigned int*)dst, 16, 0, 0);
}

#define BAR() asm volatile("s_barrier" ::: "memory")
#define VMCNT8() asm volatile("s_waitcnt vmcnt(8)" ::: "memory")
#define VMCNT0() asm volatile("s_waitcnt vmcnt(0)" ::: "memory")

// column permutation for expandT': qk cols 0..255 identity; lin (256..2303) and
// pg (2304..4351) paired into 64-col blocks [lin 32 | pg 32].
__device__ __forceinline__ int perm_col(int n) {
  if (n < 256) return n;
  int c = n - 256;
  if (c < 2048) return 256 + ((c >> 5) << 6) + (c & 31);
  c -= 2048;
  return 256 + ((c >> 5) << 6) + 32 + (c & 31);
}

// ---------------- LayerNorm: x (f32) -> nx (bf16) ----------------
__global__ __launch_bounds__(256) void ln_kernel(const float* __restrict__ x,
                                                 unsigned short* __restrict__ nx) {
  const int row = blockIdx.x;
  const int tid = threadIdx.x;
  const float4 v = reinterpret_cast<const float4*>(x + (size_t)row * DM)[tid];
  float s = v.x + v.y + v.z + v.w;
  float q = v.x * v.x + v.y * v.y + v.z * v.z + v.w * v.w;
#pragma unroll
  for (int off = 32; off > 0; off >>= 1) {
    s += __shfl_down(s, off);
    q += __shfl_down(q, off);
  }
  __shared__ float ss[4], sq[4];
  if ((tid & 63) == 0) {
    ss[tid >> 6] = s;
    sq[tid >> 6] = q;
  }
  __syncthreads();
  const float ts = ss[0] + ss[1] + ss[2] + ss[3];
  const float tq = sq[0] + sq[1] + sq[2] + sq[3];
  const float mu = ts * (1.0f / DM);
  const float var = tq * (1.0f / DM) - mu * mu;
  const float rs = rsqrtf(var + 1e-5f);
  u16x4 o;
  o[0] = f2bf((v.x - mu) * rs);
  o[1] = f2bf((v.y - mu) * rs);
  o[2] = f2bf((v.z - mu) * rs);
  o[3] = f2bf((v.w - mu) * rs);
  *reinterpret_cast<u16x4*>(nx + (size_t)row * DM + tid * 4) = o;
}

// ------- transpose+convert: in f32 [K][N] -> out bf16 [N][K], optional perm ------
template <bool PERM>
__global__ __launch_bounds__(256) void tconv_kernel(const float* __restrict__ in,
                                                    unsigned short* __restrict__ out,
                                                    int K, int N) {
  __shared__ unsigned short tile[64][72];
  const int n0 = blockIdx.x * 64;
  const int k0 = blockIdx.y * 64;
  const int tid = threadIdx.x;
  const int lr = tid >> 4, lc = (tid & 15) * 4;
#pragma unroll
  for (int p = 0; p < 4; p++) {
    const int r = lr + p * 16;
    float4 v = *reinterpret_cast<const float4*>(in + (size_t)(k0 + r) * N + n0 + lc);
    tile[r][lc + 0] = f2bf(v.x);
    tile[r][lc + 1] = f2bf(v.y);
    tile[r][lc + 2] = f2bf(v.z);
    tile[r][lc + 3] = f2bf(v.w);
  }
  __syncthreads();
  const int nn = tid >> 2, kkg = (tid & 3) * 16;
  u16x8 o0, o1;
#pragma unroll
  for (int j = 0; j < 8; j++) {
    o0[j] = tile[kkg + j][nn];
    o1[j] = tile[kkg + 8 + j][nn];
  }
  const int orow = PERM ? perm_col(n0 + nn) : (n0 + nn);
  unsigned short* dst = out + (size_t)orow * K + k0 + kkg;
  *reinterpret_cast<u16x8*>(dst) = o0;
  *reinterpret_cast<u16x8*>(dst + 8) = o1;
}

// ---------------- 256x256 8-phase GEMM: C[M,N] = A[M,K] @ Bt[N,K] (bf16) ----------
// Round-8 schedule: phase = [ds_reads; stage; (vmcnt); BAR; MFMA; BAR].
// MODE 1: f32 out = X + A@Bt^T.
// MODE 2: gated epilogue via LDS (vmcnt(0)-drained, then reused):
//   local tiles (n0<2048): lin*gelu(pg) -> concat rows, u16x8 coalesced
//   v tiles (n0>=2048):    LDS-transposed, written DIRECTLY to vT[b][d][n]
template <int MODE>
__global__ __launch_bounds__(512, 2) void gemm256_kernel(
    const unsigned short* __restrict__ A, int lda,
    const unsigned short* __restrict__ Bt, int ldb, void* __restrict__ Cv,
    void* __restrict__ Cv2, int ldc, int K, int ntn,
    const float* __restrict__ X) {
  __shared__ unsigned short G[65536];  // 128 KiB: Ah | Bh, reused by epilogue
  const int tid = threadIdx.x;
  const int lane = tid & 63;
  const int w = tid >> 6;
  const int lq = lane & 15;
  const int lg = lane >> 4;
  const int wm = w >> 2;  // 0..1
  const int wn = w & 3;   // 0..3
  const int bid = blockIdx.x;
  const int m0 = (bid / ntn) * 256;
  const int n0 = (bid % ntn) * 256;
  const int nk = K >> 6;

  auto AH = [&](int db, int kh) { return G + (db * 2 + kh) * 8192; };
  auto BH = [&](int db, int kh) { return G + 32768 + (db * 2 + kh) * 8192; };

  const int g0 = w * 64 + lane;
  const int rowS = g0 >> 2;
  const int kcS = ((g0 & 3) * 8) ^ (((rowS >> 1) & 3) << 3);
  const unsigned short* Asrc = A + (size_t)(m0 + rowS) * lda + kcS;
  const unsigned short* Bsrc = Bt + (size_t)(n0 + rowS) * ldb + kcS;
  const size_t ldaj = (size_t)128 * lda;
  const size_t ldbj = (size_t)128 * ldb;
  const int dstW = w * 64 * 8;

  auto stageA = [&](int db, int kh, int kt2) {
    if (kt2 < nk) {
      const unsigned short* s = Asrc + (size_t)kt2 * 64 + kh * 32;
      unsigned short* d = AH(db, kh) + dstW;
      gload_lds16(s, d);
      gload_lds16(s + ldaj, d + 4096);
    }
  };
  auto stageB = [&](int db, int kh, int kt2) {
    if (kt2 < nk) {
      const unsigned short* s = Bsrc + (size_t)kt2 * 64 + kh * 32;
      unsigned short* d = BH(db, kh) + dstW;
      gload_lds16(s, d);
      gload_lds16(s + ldbj, d + 4096);
    }
  };

  f32x4 acc[8][4];
#pragma unroll
  for (int i = 0; i < 8; i++)
#pragma unroll
    for (int j = 0; j < 4; j++)
#pragma unroll
      for (int r = 0; r < 4; r++) acc[i][j][r] = 0.0f;

  stageA(0, 0, 0);
  stageB(0, 0, 0);
  stageA(0, 1, 0);
  stageB(0, 1, 0);
  stageA(1, 0, 1);
  stageB(1, 0, 1);
  VMCNT8();
  BAR();

  const int aBase = wm * 128;
  const int bBase = wn * 64;
  const int cSwz = (lg * 8) ^ (((lq >> 1) & 3) << 3);

#pragma unroll 1
  for (int kt = 0; kt < nk; ++kt) {
    const int buf = kt & 1;
    bf16x8 af[4], bf0[4], bf1[4];

    // ---- phase 0: kh0, rows 0-63; stage A-kh1(kt+1)
#pragma unroll
    for (int i = 0; i < 4; i++)
      af[i] = *reinterpret_cast<const bf16x8*>(
          AH(buf, 0) + (aBase + i * 16 + lq) * 32 + cSwz);
#pragma unroll
    for (int j = 0; j < 4; j++)
      bf0[j] = *reinterpret_cast<const bf16x8*>(
          BH(buf, 0) + (bBase + j * 16 + lq) * 32 + cSwz);
    stageA(buf ^ 1, 1, kt + 1);
    BAR();
    __builtin_amdgcn_s_setprio(1);
#pragma unroll
    for (int i = 0; i < 4; i++)
#pragma unroll
      for (int j = 0; j < 4; j++)
        acc[i][j] =
            __builtin_amdgcn_mfma_f32_16x16x32_bf16(af[i], bf0[j], acc[i][j], 0, 0, 0);
    __builtin_amdgcn_s_setprio(0);
    BAR();

    // ---- phase 1: kh0, rows 64-127; stage B-kh1(kt+1); vmcnt(8)
#pragma unroll
    for (int i = 0; i < 4; i++)
      af[i] = *reinterpret_cast<const bf16x8*>(
          AH(buf, 0) + (aBase + 64 + i * 16 + lq) * 32 + cSwz);
    stageB(buf ^ 1, 1, kt + 1);
    VMCNT8();
    BAR();
    __builtin_amdgcn_s_setprio(1);
#pragma unroll
    for (int i = 0; i < 4; i++)
#pragma unroll
      for (int j = 0; j < 4; j++)
        acc[4 + i][j] = __builtin_amdgcn_mfma_f32_16x16x32_bf16(af[i], bf0[j],
                                                                acc[4 + i][j], 0, 0, 0);
    __builtin_amdgcn_s_setprio(0);
    BAR();

    // ---- phase 2: kh1, rows 0-63; stage A-kh0(kt+2)
#pragma unroll
    for (int i = 0; i < 4; i++)
      af[i] = *reinterpret_cast<const bf16x8*>(
          AH(buf, 1) + (aBase + i * 16 + lq) * 32 + cSwz);
#pragma unroll
    for (int j = 0; j < 4; j++)
      bf1[j] = *reinterpret_cast<const bf16x8*>(
          BH(buf, 1) + (bBase + j * 16 + lq) * 32 + cSwz);
    stageA(buf, 0, kt + 2);
    BAR();
    __builtin_amdgcn_s_setprio(1);
#pragma unroll
    for (int i = 0; i < 4; i++)
#pragma unroll
      for (int j = 0; j < 4; j++)
        acc[i][j] =
            __builtin_amdgcn_mfma_f32_16x16x32_bf16(af[i], bf1[j], acc[i][j], 0, 0, 0);
    __builtin_amdgcn_s_setprio(0);
    BAR();

    // ---- phase 3: kh1, rows 64-127; stage B-kh0(kt+2); vmcnt(8)
#pragma unroll
    for (int i = 0; i < 4; i++)
      af[i] = *reinterpret_cast<const bf16x8*>(
          AH(buf, 1) + (aBase + 64 + i * 16 + lq) * 32 + cSwz);
    stageB(buf, 0, kt + 2);
    VMCNT8();
    BAR();
    __builtin_amdgcn_s_setprio(1);
#pragma unroll
    for (int i = 0; i < 4; i++)
#pragma unroll
      for (int j = 0; j < 4; j++)
        acc[4 + i][j] = __builtin_amdgcn_mfma_f32_16x16x32_bf16(af[i], bf1[j],
                                                                acc[4 + i][j], 0, 0, 0);
    __builtin_amdgcn_s_setprio(0);
    BAR();
  }

  if (MODE == 1) {
    float* C = reinterpret_cast<float*>(Cv);
#pragma unroll
    for (int I = 0; I < 8; I++)
#pragma unroll
      for (int j = 0; j < 4; j++)
#pragma unroll
        for (int r = 0; r < 4; r++) {
          const int row = m0 + wm * 128 + I * 16 + lg * 4 + r;
          const int col = n0 + wn * 64 + j * 16 + lq;
          const size_t off = (size_t)row * ldc + col;
          C[off] = X[off] + acc[I][j][r];
        }
  } else {
    // MODE 2: drain staging queue before reusing LDS (per-wave vmcnt + barrier)
    VMCNT0();
    BAR();
    unsigned short* concat = reinterpret_cast<unsigned short*>(Cv);
    unsigned short* vT = reinterpret_cast<unsigned short*>(Cv2);
    if (n0 < 2048) {
      // local tile: gated cols [n0/2, n0/2+128) -> concat rows, coalesced
      const int c0 = n0 >> 1;
#pragma unroll
      for (int I = 0; I < 8; I++)
#pragma unroll
        for (int j = 0; j < 2; j++)
#pragma unroll
          for (int r = 0; r < 4; r++) {
            const float g = acc[I][j][r] * gelu_fast(acc[I][j + 2][r]);
            G[(wm * 128 + I * 16 + lg * 4 + r) * 136 + wn * 32 + j * 16 + lq] =
                f2bf(g);
          }
      BAR();
#pragma unroll
      for (int it = 0; it < 8; ++it) {
        const int chunk = tid + it * 512;
        const int row = chunk >> 4, cc = chunk & 15;
        *reinterpret_cast<u16x8*>(concat + (size_t)(m0 + row) * 2048 + c0 +
                                  cc * 8) =
            *reinterpret_cast<const u16x8*>(&G[row * 136 + cc * 8]);
      }
    } else {
      // v tile: transpose in LDS, write vT[b][d][n] directly
      const int d0 = (n0 >> 1) - 1024;
      const int b = m0 >> 12;
      const int nn0 = m0 & 4095;
#pragma unroll
      for (int I = 0; I < 8; I++)
#pragma unroll
        for (int j = 0; j < 2; j++)
#pragma unroll
          for (int r = 0; r < 4; r++) {
            const float g = acc[I][j][r] * gelu_fast(acc[I][j + 2][r]);
            G[(wn * 32 + j * 16 + lq) * 264 + wm * 128 + I * 16 + lg * 4 + r] =
                f2bf(g);
          }
      BAR();
#pragma unroll
      for (int it = 0; it < 8; ++it) {
        const int chunk = tid + it * 512;
        const int d = chunk >> 5, cc = chunk & 31;
        *reinterpret_cast<u16x8*>(vT + (size_t)(b * 1024 + d0 + d) * 4096 +
                                  nn0 + cc * 8) =
            *reinterpret_cast<const u16x8*>(&G[d * 264 + cc * 8]);
      }
    }
  }
}

// ---------------- qk kernel: qk[16384][256] = nx @ expandT[0:256]^T -------------
__global__ __launch_bounds__(256, 4) void qk_kernel(
    const unsigned short* __restrict__ nx, const unsigned short* __restrict__ eT,
    unsigned short* __restrict__ qk) {
  __shared__ unsigned short As[128][64];
  __shared__ unsigned short Bs[128][64];
  const int tid = threadIdx.x;
  const int m0 = (blockIdx.x >> 1) * 128;
  const int n0 = (blockIdx.x & 1) * 128;
  const int lane = tid & 63;
  const int w = tid >> 6;
  const int lr = lane & 15;
  const int lg = lane >> 4;
  const int wr = (w >> 1) * 64;
  const int wc = (w & 1) * 64;
  const int rSwz = (lr & 7) << 3;

  f32x4 acc[4][4];
#pragma unroll
  for (int i = 0; i < 4; i++)
#pragma unroll
    for (int j = 0; j < 4; j++)
#pragma unroll
      for (int r = 0; r < 4; r++) acc[i][j][r] = 0.0f;

  for (int k0 = 0; k0 < 1024; k0 += 64) {
#pragma unroll
    for (int j = 0; j < 4; j++) {
      const int boff = w * 4096 + j * 1024 + lane * 16;
      const int row = boff >> 7;
      const int col = (((boff & 127) >> 1)) ^ ((row & 7) << 3);
      gload_lds16(nx + (size_t)(m0 + row) * DM + k0 + col,
                  &As[0][0] + (boff - lane * 16) / 2);
    }
#pragma unroll
    for (int j = 0; j < 4; j++) {
      const int boff = w * 4096 + j * 1024 + lane * 16;
      const int row = boff >> 7;
      const int col = (((boff & 127) >> 1)) ^ ((row & 7) << 3);
      gload_lds16(eT + (size_t)(n0 + row) * DM + k0 + col,
                  &Bs[0][0] + (boff - lane * 16) / 2);
    }
    __syncthreads();
#pragma unroll
    for (int kk = 0; kk < 64; kk += 32) {
      bf16x8 af[4], bfr[4];
#pragma unroll
      for (int i = 0; i < 4; i++)
        af[i] = *reinterpret_cast<const bf16x8*>(
            &As[wr + i * 16 + lr][(kk + lg * 8) ^ rSwz]);
#pragma unroll
      for (int j = 0; j < 4; j++)
        bfr[j] = *reinterpret_cast<const bf16x8*>(
            &Bs[wc + j * 16 + lr][(kk + lg * 8) ^ rSwz]);
#pragma unroll
      for (int i = 0; i < 4; i++)
#pragma unroll
        for (int j = 0; j < 4; j++)
          acc[i][j] = __builtin_amdgcn_mfma_f32_16x16x32_bf16(af[i], bfr[j],
                                                              acc[i][j], 0, 0, 0);
    }
    __syncthreads();
  }

#pragma unroll
  for (int i = 0; i < 4; i++)
#pragma unroll
    for (int j = 0; j < 4; j++)
#pragma unroll
      for (int r = 0; r < 4; r++) {
        const int row = m0 + wr + i * 16 + lg * 4 + r;
        const int col = n0 + wc + j * 16 + lr;
        qk[(size_t)row * 256 + col] = f2bf(acc[i][j][r]);
      }
}

// ---------------- P kernel: one causal 128x128 tile per block --------------------
#define P_TILE 16384           // 128*128
#define P_PER_B 8650752        // 528 tiles * 16384
__global__ __launch_bounds__(512, 4) void pk_kernel(
    const unsigned short* __restrict__ qk, const float* __restrict__ pbm_ptr,
    unsigned short* __restrict__ P, float* __restrict__ l) {
  __shared__ unsigned short Ks[128][136];
  const int tid = threadIdx.x;
  const int lane = tid & 63;
  const int w = tid >> 6;
  const int lq = lane & 15;
  const int lg = lane >> 4;
  const int bid = blockIdx.x;
  const int b = bid / 528;
  const int t = bid - b * 528;
  int qt = (int)((sqrtf((float)(8 * t + 1)) - 1.0f) * 0.5f);
  while ((qt + 1) * (qt + 2) / 2 <= t) ++qt;
  while (qt * (qt + 1) / 2 > t) --qt;
  const int kt = t - qt * (qt + 1) / 2;
  const float pbm = *pbm_ptr;
  const float SCALE = 0.08838834764831845f;

  const unsigned short* qb = qk + (size_t)b * NSEQ * 256;

#pragma unroll
  for (int p = 0; p < 4; p++) {
    const int task = tid + p * 512;
    const int row = task >> 4;
    const int ch = task & 15;
    bf16x8 v = *reinterpret_cast<const bf16x8*>(
        qb + (size_t)(kt * 128 + row) * 256 + 128 + ch * 8);
    *reinterpret_cast<bf16x8*>(&Ks[row][ch * 8]) = v;
  }
  const int qloc = w * 16 + lq;
  bf16x8 qf[4];
#pragma unroll
  for (int ks = 0; ks < 4; ks++)
    qf[ks] = *reinterpret_cast<const bf16x8*>(
        qb + (size_t)(qt * 128 + qloc) * 256 + ks * 32 + lg * 8);
  __syncthreads();

  f32x4 sa[8];
#pragma unroll
  for (int sub = 0; sub < 8; sub++)
#pragma unroll
    for (int r = 0; r < 4; r++) sa[sub][r] = 0.0f;
#pragma unroll
  for (int ks = 0; ks < 4; ks++)
#pragma unroll
    for (int sub = 0; sub < 8; sub++) {
      bf16x8 kf =
          *reinterpret_cast<const bf16x8*>(&Ks[sub * 16 + lq][ks * 32 + lg * 8]);
      sa[sub] = __builtin_amdgcn_mfma_f32_16x16x32_bf16(kf, qf[ks], sa[sub], 0, 0, 0);
    }
  const size_t KL = (size_t)(qt + 1) * 128;
  unsigned short* Prow = P + (size_t)b * P_PER_B +
                         (size_t)(qt * (qt + 1) / 2) * P_TILE + (size_t)qloc * KL +
                         kt * 128;
  float ps = 0.0f;
  const bool diag = (kt == qt);
#pragma unroll
  for (int sub = 0; sub < 8; sub++) {
    bf16x4v pv;
#pragma unroll
    for (int r = 0; r < 4; r++) {
      const int kvloc = sub * 16 + lg * 4 + r;
      float p;
      if (diag && kvloc > qloc) {
        p = 0.0f;
      } else {
        const float dn = (float)((kt - qt) * 128 + kvloc - qloc) + pbm;
        const float s = sa[sub][r] * SCALE + 1.0f / (1.0f + __expf(-dn));
        p = __expf(s);
      }
      ps += p;
      pv[r] = (__bf16)p;
    }
    *reinterpret_cast<bf16x4v*>(Prow + sub * 16 + lg * 4) = pv;
  }
  ps += __shfl_xor(ps, 16);
  ps += __shfl_xor(ps, 32);
  if (lane < 16) atomicAdd(&l[b * NSEQ + qt * 128 + w * 16 + lane], ps);
}

// ---------------- PV kernel: O[128, 128] = P[128, KL] @ vT^T, /l, -> concat ------
// Epilogue routed through LDS for coalesced u16x8 stores.
__global__ __launch_bounds__(256, 4) void pv_kernel(
    const unsigned short* __restrict__ P, const unsigned short* __restrict__ vT,
    const float* __restrict__ l, unsigned short* __restrict__ concat) {
  __shared__ unsigned short LDSp[17408];  // As | Bs; epilogue reuses as [128][136]
  unsigned short* Asb = LDSp;
  unsigned short* Bsb = LDSp + 8192;
  const int tid = threadIdx.x;
  const int bid = blockIdx.x;
  const int qt = 31 - (bid >> 5);
  const int rest = bid & 31;
  const int b = rest >> 3;
  const int nt = rest & 7;
  const int KL = (qt + 1) * 128;
  const unsigned short* A =
      P + (size_t)b * P_PER_B + (size_t)(qt * (qt + 1) / 2) * P_TILE;
  const unsigned short* Bt = vT + (size_t)b * DM * NSEQ;
  const int n0 = nt * 128;
  const int lane = tid & 63;
  const int w = tid >> 6;
  const int lr = lane & 15;
  const int lg = lane >> 4;
  const int wr = (w >> 1) * 64;
  const int wc = (w & 1) * 64;
  const int rSwz = (lr & 7) << 3;

  f32x4 acc[4][4];
#pragma unroll
  for (int i = 0; i < 4; i++)
#pragma unroll
    for (int j = 0; j < 4; j++)
#pragma unroll
      for (int r = 0; r < 4; r++) acc[i][j][r] = 0.0f;

  for (int k0 = 0; k0 < KL; k0 += 64) {
#pragma unroll
    for (int j = 0; j < 4; j++) {
      const int boff = w * 4096 + j * 1024 + lane * 16;
      const int row = boff >> 7;
      const int col = (((boff & 127) >> 1)) ^ ((row & 7) << 3);
      gload_lds16(A + (size_t)row * KL + k0 + col,
                  Asb + (boff - lane * 16) / 2);
    }
#pragma unroll
    for (int j = 0; j < 4; j++) {
      const int boff = w * 4096 + j * 1024 + lane * 16;
      const int row = boff >> 7;
      const int col = (((boff & 127) >> 1)) ^ ((row & 7) << 3);
      gload_lds16(Bt + (size_t)(n0 + row) * NSEQ + k0 + col,
                  Bsb + (boff - lane * 16) / 2);
    }
    __syncthreads();
#pragma unroll
    for (int kk = 0; kk < 64; kk += 32) {
      bf16x8 af[4], bfr[4];
#pragma unroll
      for (int i = 0; i < 4; i++)
        af[i] = *reinterpret_cast<const bf16x8*>(
            Asb + (wr + i * 16 + lr) * 64 + ((kk + lg * 8) ^ rSwz));
#pragma unroll
      for (int j = 0; j < 4; j++)
        bfr[j] = *reinterpret_cast<const bf16x8*>(
            Bsb + (wc + j * 16 + lr) * 64 + ((kk + lg * 8) ^ rSwz));
#pragma unroll
      for (int i = 0; i < 4; i++)
#pragma unroll
        for (int j = 0; j < 4; j++)
          acc[i][j] = __builtin_amdgcn_mfma_f32_16x16x32_bf16(af[i], bfr[j],
                                                              acc[i][j], 0, 0, 0);
    }
    __syncthreads();
  }

  const float* lb = l + b * NSEQ + qt * 128;
#pragma unroll
  for (int i = 0; i < 4; i++) {
    f32x4 lv = *reinterpret_cast<const f32x4*>(&lb[wr + i * 16 + lg * 4]);
    f32x4 inv;
#pragma unroll
    for (int r = 0; r < 4; r++) inv[r] = 1.0f / lv[r];
#pragma unroll
    for (int j = 0; j < 4; j++)
#pragma unroll
      for (int r = 0; r < 4; r++)
        LDSp[(wr + i * 16 + lg * 4 + r) * 136 + wc + j * 16 + lr] =
            f2bf(acc[i][j][r] * inv[r]);
  }
  __syncthreads();
#pragma unroll
  for (int it = 0; it < 8; ++it) {
    const int chunk = tid + it * 256;  // 2048 chunks = 128 rows x 16
    const int row = chunk >> 4, cc = chunk & 15;
    *reinterpret_cast<u16x8*>(concat +
                              (size_t)(b * NSEQ + qt * 128 + row) * 2048 + 1024 +
                              n0 + cc * 8) =
        *reinterpret_cast<const u16x8*>(&LDSp[row * 136 + cc * 8]);
  }
}

extern "C" void kernel_launch(void* const* d_in, const int* in_sizes, int n_in,
                              void* d_out, int out_size, void* d_ws,
                              size_t ws_size, hipStream_t stream) {
  (void)in_sizes;
  (void)n_in;
  (void)out_size;
  const float* x = (const float*)d_in[0];
  const float* expand = (const float*)d_in[1];
  const float* project = (const float*)d_in[2];
  const float* pbm = (const float*)d_in[3];
  float* out = (float*)d_out;

  // Region map:
  // [0, 8.4)       qk [16384][256]
  // [8.4, 41.9)    vT [4][1024][4096]   (written by gate GEMM epilogue)
  // [41.9, 111.2)  P (causal-packed)
  // [111.2,+64K)   l
  // [111.3, 120.2) expandT' (permuted, 4352x1024)
  // [142.6, 209.7) concat
  // [209.7, 243.3) nx  (projectT aliases after gate GEMM+qk consume nx)
  const size_t QK_BYTES = (size_t)16384 * 256 * 2;
  const size_t VT_BYTES = (size_t)16384 * 1024 * 2;
  const size_t P_BYTES = (size_t)NBATCH * P_PER_B * 2;
  const size_t L_BYTES = (size_t)NBATCH * NSEQ * 4;
  const size_t GH_BYTES = (size_t)16384 * 4096 * 2;
  const size_t CAT_BYTES = (size_t)16384 * 2048 * 2;
  const size_t NX_BYTES = (size_t)16384 * DM * 2;
  if (ws_size < QK_BYTES + GH_BYTES + CAT_BYTES + NX_BYTES) return;

  char* ws = (char*)d_ws;
  unsigned short* qk = (unsigned short*)ws;
  unsigned short* vT = (unsigned short*)(ws + QK_BYTES);
  unsigned short* P = (unsigned short*)(ws + QK_BYTES + VT_BYTES);
  float* l = (float*)(ws + QK_BYTES + VT_BYTES + P_BYTES);
  unsigned short* expandT =
      (unsigned short*)(ws + QK_BYTES + VT_BYTES + P_BYTES + L_BYTES);
  unsigned short* concat = (unsigned short*)(ws + QK_BYTES + GH_BYTES);
  unsigned short* nx = (unsigned short*)(ws + QK_BYTES + GH_BYTES + CAT_BYTES);
  unsigned short* projectT = nx;

  // 0a. expandT'[perm(n)][k] = bf16(expand[k][n])
  tconv_kernel<true><<<dim3(68, 16), 256, 0, stream>>>(expand, expandT, 1024, 4352);
  // 1. LayerNorm
  ln_kernel<<<16384, 256, 0, stream>>>(x, nx);
  // 2a. qk = nx @ expandT'[0:256]^T  (128-tile, 256 blocks)
  qk_kernel<<<dim3(256), 256, 0, stream>>>(nx, expandT, qk);
  // 2b. gated GEMM (ntn=16): local->concat[:, :1024], v->vT (transposed, fused)
  gemm256_kernel<2><<<dim3(64 * 16), 512, 0, stream>>>(
      nx, DM, expandT + (size_t)256 * DM, DM, (void*)concat, (void*)vT, 0, DM,
      16, nullptr);
  // 3. P = softmax numerator; l zeroed first
  hipMemsetAsync(l, 0, L_BYTES, stream);
  pk_kernel<<<dim3(NBATCH * 528), 512, 0, stream>>>(qk, pbm, P, l);
  // 4. attn = (P @ V) / l -> concat[:, 1024:2048]
  pv_kernel<<<dim3(1024), 256, 0, stream>>>(P, vT, l, concat);
  // 5. projectT (nx dead after 2a/2b)
  tconv_kernel<false><<<dim3(16, 32), 256, 0, stream>>>(project, projectT, 2048, DM);
  // 6. out = x + concat @ projectT^T
  gemm256_kernel<1><<<dim3(64 * 4), 512, 0, stream>>>(
      concat, 2048, projectT, 2048, (void*)out, nullptr, DM, 2048, 4, x);
}

// Round 14
// 422.446 us; speedup vs baseline: 1.1252x; 1.0145x over previous
//
#include <hip/hip_runtime.h>
#include <type_traits>

typedef __bf16 bf16x8 __attribute__((ext_vector_type(8)));
typedef __bf16 bf16x4v __attribute__((ext_vector_type(4)));
typedef float f32x4 __attribute__((ext_vector_type(4)));
typedef unsigned short u16x8 __attribute__((ext_vector_type(8)));
typedef unsigned short u16x4 __attribute__((ext_vector_type(4)));

#define NSEQ 4096
#define DM 1024
#define NBATCH 4

__device__ __forceinline__ unsigned short f2bf(float f) {
  unsigned u = __float_as_uint(f);
  u += 0x7FFFu + ((u >> 16) & 1u);
  return (unsigned short)(u >> 16);
}
__device__ __forceinline__ float bf2f(unsigned short h) {
  return __uint_as_float(((unsigned)h) << 16);
}
// branch-free tanh-approx gelu (round-11, verified absmax 0.03125)
__device__ __forceinline__ float gelu_fast(float x) {
  const float y = 1.5957691216057308f * (x + 0.044715f * x * x * x);
  return x / (1.0f + __expf(-y));
}

// async global->LDS, 16B per lane; lds dst is wave-uniform base + lane*16
__device__ __forceinline__ void gload_lds16(const unsigned short* src,
                                            unsigned short* dst) {
  __builtin_amdgcn_global_load_lds(
      (const __attribute__((address_space(1))) unsigned int*)src,
      (__attribute__((address_space(3))) unsigned int*)dst, 16, 0, 0);
}

#define BAR() asm volatile("s_barrier" ::: "memory")
#define VMCNT8() asm volatile("s_waitcnt vmcnt(8)" ::: "memory")
#define VMCNT0() asm volatile("s_waitcnt vmcnt(0)" ::: "memory")

// column permutation for expandT': qk cols 0..255 identity; lin (256..2303) and
// pg (2304..4351) paired into 64-col blocks [lin 32 | pg 32].
__device__ __forceinline__ int perm_col(int n) {
  if (n < 256) return n;
  int c = n - 256;
  if (c < 2048) return 256 + ((c >> 5) << 6) + (c & 31);
  c -= 2048;
  return 256 + ((c >> 5) << 6) + 32 + (c & 31);
}

// ---------------- LayerNorm: x (f32) -> nx (bf16) ----------------
__global__ __launch_bounds__(256) void ln_kernel(const float* __restrict__ x,
                                                 unsigned short* __restrict__ nx) {
  const int row = blockIdx.x;
  const int tid = threadIdx.x;
  const float4 v = reinterpret_cast<const float4*>(x + (size_t)row * DM)[tid];
  float s = v.x + v.y + v.z + v.w;
  float q = v.x * v.x + v.y * v.y + v.z * v.z + v.w * v.w;
#pragma unroll
  for (int off = 32; off > 0; off >>= 1) {
    s += __shfl_down(s, off);
    q += __shfl_down(q, off);
  }
  __shared__ float ss[4], sq[4];
  if ((tid & 63) == 0) {
    ss[tid >> 6] = s;
    sq[tid >> 6] = q;
  }
  __syncthreads();
  const float ts = ss[0] + ss[1] + ss[2] + ss[3];
  const float tq = sq[0] + sq[1] + sq[2] + sq[3];
  const float mu = ts * (1.0f / DM);
  const float var = tq * (1.0f / DM) - mu * mu;
  const float rs = rsqrtf(var + 1e-5f);
  u16x4 o;
  o[0] = f2bf((v.x - mu) * rs);
  o[1] = f2bf((v.y - mu) * rs);
  o[2] = f2bf((v.z - mu) * rs);
  o[3] = f2bf((v.w - mu) * rs);
  *reinterpret_cast<u16x4*>(nx + (size_t)row * DM + tid * 4) = o;
}

// ------- transpose+convert: in f32 [K][N] -> out bf16 [N][K], optional perm ------
template <bool PERM>
__global__ __launch_bounds__(256) void tconv_kernel(const float* __restrict__ in,
                                                    unsigned short* __restrict__ out,
                                                    int K, int N) {
  __shared__ unsigned short tile[64][72];
  const int n0 = blockIdx.x * 64;
  const int k0 = blockIdx.y * 64;
  const int tid = threadIdx.x;
  const int lr = tid >> 4, lc = (tid & 15) * 4;
#pragma unroll
  for (int p = 0; p < 4; p++) {
    const int r = lr + p * 16;
    float4 v = *reinterpret_cast<const float4*>(in + (size_t)(k0 + r) * N + n0 + lc);
    tile[r][lc + 0] = f2bf(v.x);
    tile[r][lc + 1] = f2bf(v.y);
    tile[r][lc + 2] = f2bf(v.z);
    tile[r][lc + 3] = f2bf(v.w);
  }
  __syncthreads();
  const int nn = tid >> 2, kkg = (tid & 3) * 16;
  u16x8 o0, o1;
#pragma unroll
  for (int j = 0; j < 8; j++) {
    o0[j] = tile[kkg + j][nn];
    o1[j] = tile[kkg + 8 + j][nn];
  }
  const int orow = PERM ? perm_col(n0 + nn) : (n0 + nn);
  unsigned short* dst = out + (size_t)orow * K + k0 + kkg;
  *reinterpret_cast<u16x8*>(dst) = o0;
  *reinterpret_cast<u16x8*>(dst + 8) = o1;
}

// ---------------- 256x256 8-phase GEMM: C[M,N] = A[M,K] @ Bt[N,K] (bf16) ----------
// Round-8 schedule: phase = [ds_reads; stage; (vmcnt); BAR; MFMA; BAR].
// MODE 1: f32 out = X + A@Bt^T  (bid -> (bid/ntn, bid%ntn)).
// MODE 2: fused expand GEMM over permuted expandT', grid 1088:
//   bid <  64 : qk tile (mt=bid, nt=0)    -> raw bf16 store to qk[16384][256]
//   bid >= 64 : gate tile (mt=(bid-64)/16, nt=1+(bid-64)%16); gated epilogue via
//               LDS: local -> concat rows, v -> vT[b][d][n] (transposed).
//   qk tiles first so they backfill the 4.25-round grid (equal-weight blocks).
template <int MODE>
__global__ __launch_bounds__(512, 2) void gemm256_kernel(
    const unsigned short* __restrict__ A, int lda,
    const unsigned short* __restrict__ Bt, int ldb, void* __restrict__ Cv,
    void* __restrict__ Cv2, void* __restrict__ Cv3, int ldc, int K, int ntn,
    const float* __restrict__ X) {
  __shared__ unsigned short G[65536];  // 128 KiB: Ah | Bh, reused by epilogue
  const int tid = threadIdx.x;
  const int lane = tid & 63;
  const int w = tid >> 6;
  const int lq = lane & 15;
  const int lg = lane >> 4;
  const int wm = w >> 2;  // 0..1
  const int wn = w & 3;   // 0..3
  const int bid = blockIdx.x;
  int m0, n0;
  if (MODE == 2) {
    if (bid < 64) {
      m0 = bid * 256;
      n0 = 0;
    } else {
      m0 = ((bid - 64) >> 4) * 256;
      n0 = (1 + ((bid - 64) & 15)) * 256;
    }
  } else {
    m0 = (bid / ntn) * 256;
    n0 = (bid % ntn) * 256;
  }
  const int nk = K >> 6;

  auto AH = [&](int db, int kh) { return G + (db * 2 + kh) * 8192; };
  auto BH = [&](int db, int kh) { return G + 32768 + (db * 2 + kh) * 8192; };

  const int g0 = w * 64 + lane;
  const int rowS = g0 >> 2;
  const int kcS = ((g0 & 3) * 8) ^ (((rowS >> 1) & 3) << 3);
  const unsigned short* Asrc = A + (size_t)(m0 + rowS) * lda + kcS;
  const unsigned short* Bsrc = Bt + (size_t)(n0 + rowS) * ldb + kcS;
  const size_t ldaj = (size_t)128 * lda;
  const size_t ldbj = (size_t)128 * ldb;
  const int dstW = w * 64 * 8;

  auto stageA = [&](int db, int kh, int kt2) {
    if (kt2 < nk) {
      const unsigned short* s = Asrc + (size_t)kt2 * 64 + kh * 32;
      unsigned short* d = AH(db, kh) + dstW;
      gload_lds16(s, d);
      gload_lds16(s + ldaj, d + 4096);
    }
  };
  auto stageB = [&](int db, int kh, int kt2) {
    if (kt2 < nk) {
      const unsigned short* s = Bsrc + (size_t)kt2 * 64 + kh * 32;
      unsigned short* d = BH(db, kh) + dstW;
      gload_lds16(s, d);
      gload_lds16(s + ldbj, d + 4096);
    }
  };

  f32x4 acc[8][4];
#pragma unroll
  for (int i = 0; i < 8; i++)
#pragma unroll
    for (int j = 0; j < 4; j++)
#pragma unroll
      for (int r = 0; r < 4; r++) acc[i][j][r] = 0.0f;

  stageA(0, 0, 0);
  stageB(0, 0, 0);
  stageA(0, 1, 0);
  stageB(0, 1, 0);
  stageA(1, 0, 1);
  stageB(1, 0, 1);
  VMCNT8();
  BAR();

  const int aBase = wm * 128;
  const int bBase = wn * 64;
  const int cSwz = (lg * 8) ^ (((lq >> 1) & 3) << 3);

#pragma unroll 1
  for (int kt = 0; kt < nk; ++kt) {
    const int buf = kt & 1;
    bf16x8 af[4], bf0[4], bf1[4];

    // ---- phase 0: kh0, rows 0-63; stage A-kh1(kt+1)
#pragma unroll
    for (int i = 0; i < 4; i++)
      af[i] = *reinterpret_cast<const bf16x8*>(
          AH(buf, 0) + (aBase + i * 16 + lq) * 32 + cSwz);
#pragma unroll
    for (int j = 0; j < 4; j++)
      bf0[j] = *reinterpret_cast<const bf16x8*>(
          BH(buf, 0) + (bBase + j * 16 + lq) * 32 + cSwz);
    stageA(buf ^ 1, 1, kt + 1);
    BAR();
    __builtin_amdgcn_s_setprio(1);
#pragma unroll
    for (int i = 0; i < 4; i++)
#pragma unroll
      for (int j = 0; j < 4; j++)
        acc[i][j] =
            __builtin_amdgcn_mfma_f32_16x16x32_bf16(af[i], bf0[j], acc[i][j], 0, 0, 0);
    __builtin_amdgcn_s_setprio(0);
    BAR();

    // ---- phase 1: kh0, rows 64-127; stage B-kh1(kt+1); vmcnt(8)
#pragma unroll
    for (int i = 0; i < 4; i++)
      af[i] = *reinterpret_cast<const bf16x8*>(
          AH(buf, 0) + (aBase + 64 + i * 16 + lq) * 32 + cSwz);
    stageB(buf ^ 1, 1, kt + 1);
    VMCNT8();
    BAR();
    __builtin_amdgcn_s_setprio(1);
#pragma unroll
    for (int i = 0; i < 4; i++)
#pragma unroll
      for (int j = 0; j < 4; j++)
        acc[4 + i][j] = __builtin_amdgcn_mfma_f32_16x16x32_bf16(af[i], bf0[j],
                                                                acc[4 + i][j], 0, 0, 0);
    __builtin_amdgcn_s_setprio(0);
    BAR();

    // ---- phase 2: kh1, rows 0-63; stage A-kh0(kt+2)
#pragma unroll
    for (int i = 0; i < 4; i++)
      af[i] = *reinterpret_cast<const bf16x8*>(
          AH(buf, 1) + (aBase + i * 16 + lq) * 32 + cSwz);
#pragma unroll
    for (int j = 0; j < 4; j++)
      bf1[j] = *reinterpret_cast<const bf16x8*>(
          BH(buf, 1) + (bBase + j * 16 + lq) * 32 + cSwz);
    stageA(buf, 0, kt + 2);
    BAR();
    __builtin_amdgcn_s_setprio(1);
#pragma unroll
    for (int i = 0; i < 4; i++)
#pragma unroll
      for (int j = 0; j < 4; j++)
        acc[i][j] =
            __builtin_amdgcn_mfma_f32_16x16x32_bf16(af[i], bf1[j], acc[i][j], 0, 0, 0);
    __builtin_amdgcn_s_setprio(0);
    BAR();

    // ---- phase 3: kh1, rows 64-127; stage B-kh0(kt+2); vmcnt(8)
#pragma unroll
    for (int i = 0; i < 4; i++)
      af[i] = *reinterpret_cast<const bf16x8*>(
          AH(buf, 1) + (aBase + 64 + i * 16 + lq) * 32 + cSwz);
    stageB(buf, 0, kt + 2);
    VMCNT8();
    BAR();
    __builtin_amdgcn_s_setprio(1);
#pragma unroll
    for (int i = 0; i < 4; i++)
#pragma unroll
      for (int j = 0; j < 4; j++)
        acc[4 + i][j] = __builtin_amdgcn_mfma_f32_16x16x32_bf16(af[i], bf1[j],
                                                                acc[4 + i][j], 0, 0, 0);
    __builtin_amdgcn_s_setprio(0);
    BAR();
  }

  if (MODE == 1) {
    float* C = reinterpret_cast<float*>(Cv);
#pragma unroll
    for (int I = 0; I < 8; I++)
#pragma unroll
      for (int j = 0; j < 4; j++)
#pragma unroll
        for (int r = 0; r < 4; r++) {
          const int row = m0 + wm * 128 + I * 16 + lg * 4 + r;
          const int col = n0 + wn * 64 + j * 16 + lq;
          const size_t off = (size_t)row * ldc + col;
          C[off] = X[off] + acc[I][j][r];
        }
  } else {
    // MODE 2: drain staging queue before reusing LDS
    VMCNT0();
    BAR();
    unsigned short* concat = reinterpret_cast<unsigned short*>(Cv);
    unsigned short* vT = reinterpret_cast<unsigned short*>(Cv2);
    if (n0 == 0) {
      // qk tile: raw bf16 store (cols 0..255 of expandT' are identity)
      unsigned short* qkp = reinterpret_cast<unsigned short*>(Cv3);
#pragma unroll
      for (int I = 0; I < 8; I++)
#pragma unroll
        for (int j = 0; j < 4; j++)
#pragma unroll
          for (int r = 0; r < 4; r++) {
            const int row = m0 + wm * 128 + I * 16 + lg * 4 + r;
            const int col = wn * 64 + j * 16 + lq;
            qkp[(size_t)row * 256 + col] = f2bf(acc[I][j][r]);
          }
    } else if (n0 < 2304) {
      // local tile: gated cols [(n0-256)/2, +128) -> concat rows, coalesced
      const int c0 = (n0 - 256) >> 1;
#pragma unroll
      for (int I = 0; I < 8; I++)
#pragma unroll
        for (int j = 0; j < 2; j++)
#pragma unroll
          for (int r = 0; r < 4; r++) {
            const float g = acc[I][j][r] * gelu_fast(acc[I][j + 2][r]);
            G[(wm * 128 + I * 16 + lg * 4 + r) * 136 + wn * 32 + j * 16 + lq] =
                f2bf(g);
          }
      BAR();
#pragma unroll
      for (int it = 0; it < 8; ++it) {
        const int chunk = tid + it * 512;
        const int row = chunk >> 4, cc = chunk & 15;
        *reinterpret_cast<u16x8*>(concat + (size_t)(m0 + row) * 2048 + c0 +
                                  cc * 8) =
            *reinterpret_cast<const u16x8*>(&G[row * 136 + cc * 8]);
      }
    } else {
      // v tile: transpose in LDS, write vT[b][d][n] directly
      const int d0 = ((n0 - 256) >> 1) - 1024;
      const int b = m0 >> 12;
      const int nn0 = m0 & 4095;
#pragma unroll
      for (int I = 0; I < 8; I++)
#pragma unroll
        for (int j = 0; j < 2; j++)
#pragma unroll
          for (int r = 0; r < 4; r++) {
            const float g = acc[I][j][r] * gelu_fast(acc[I][j + 2][r]);
            G[(wn * 32 + j * 16 + lq) * 264 + wm * 128 + I * 16 + lg * 4 + r] =
                f2bf(g);
          }
      BAR();
#pragma unroll
      for (int it = 0; it < 8; ++it) {
        const int chunk = tid + it * 512;
        const int d = chunk >> 5, cc = chunk & 31;
        *reinterpret_cast<u16x8*>(vT + (size_t)(b * 1024 + d0 + d) * 4096 +
                                  nn0 + cc * 8) =
            *reinterpret_cast<const u16x8*>(&G[d * 264 + cc * 8]);
      }
    }
  }
}

// ---------------- P kernel: one causal 128x128 tile per block --------------------
#define P_TILE 16384           // 128*128
#define P_PER_B 8650752        // 528 tiles * 16384
__global__ __launch_bounds__(512, 4) void pk_kernel(
    const unsigned short* __restrict__ qk, const float* __restrict__ pbm_ptr,
    unsigned short* __restrict__ P, float* __restrict__ l) {
  __shared__ unsigned short Ks[128][136];
  const int tid = threadIdx.x;
  const int lane = tid & 63;
  const int w = tid >> 6;
  const int lq = lane & 15;
  const int lg = lane >> 4;
  const int bid = blockIdx.x;
  const int b = bid / 528;
  const int t = bid - b * 528;
  int qt = (int)((sqrtf((float)(8 * t + 1)) - 1.0f) * 0.5f);
  while ((qt + 1) * (qt + 2) / 2 <= t) ++qt;
  while (qt * (qt + 1) / 2 > t) --qt;
  const int kt = t - qt * (qt + 1) / 2;
  const float pbm = *pbm_ptr;
  const float SCALE = 0.08838834764831845f;

  const unsigned short* qb = qk + (size_t)b * NSEQ * 256;

#pragma unroll
  for (int p = 0; p < 4; p++) {
    const int task = tid + p * 512;
    const int row = task >> 4;
    const int ch = task & 15;
    bf16x8 v = *reinterpret_cast<const bf16x8*>(
        qb + (size_t)(kt * 128 + row) * 256 + 128 + ch * 8);
    *reinterpret_cast<bf16x8*>(&Ks[row][ch * 8]) = v;
  }
  const int qloc = w * 16 + lq;
  bf16x8 qf[4];
#pragma unroll
  for (int ks = 0; ks < 4; ks++)
    qf[ks] = *reinterpret_cast<const bf16x8*>(
        qb + (size_t)(qt * 128 + qloc) * 256 + ks * 32 + lg * 8);
  __syncthreads();

  f32x4 sa[8];
#pragma unroll
  for (int sub = 0; sub < 8; sub++)
#pragma unroll
    for (int r = 0; r < 4; r++) sa[sub][r] = 0.0f;
#pragma unroll
  for (int ks = 0; ks < 4; ks++)
#pragma unroll
    for (int sub = 0; sub < 8; sub++) {
      bf16x8 kf =
          *reinterpret_cast<const bf16x8*>(&Ks[sub * 16 + lq][ks * 32 + lg * 8]);
      sa[sub] = __builtin_amdgcn_mfma_f32_16x16x32_bf16(kf, qf[ks], sa[sub], 0, 0, 0);
    }
  const size_t KL = (size_t)(qt + 1) * 128;
  unsigned short* Prow = P + (size_t)b * P_PER_B +
                         (size_t)(qt * (qt + 1) / 2) * P_TILE + (size_t)qloc * KL +
                         kt * 128;
  float ps = 0.0f;
  const bool diag = (kt == qt);
#pragma unroll
  for (int sub = 0; sub < 8; sub++) {
    bf16x4v pv;
#pragma unroll
    for (int r = 0; r < 4; r++) {
      const int kvloc = sub * 16 + lg * 4 + r;
      float p;
      if (diag && kvloc > qloc) {
        p = 0.0f;
      } else {
        const float dn = (float)((kt - qt) * 128 + kvloc - qloc) + pbm;
        const float s = sa[sub][r] * SCALE + 1.0f / (1.0f + __expf(-dn));
        p = __expf(s);
      }
      ps += p;
      pv[r] = (__bf16)p;
    }
    *reinterpret_cast<bf16x4v*>(Prow + sub * 16 + lg * 4) = pv;
  }
  ps += __shfl_xor(ps, 16);
  ps += __shfl_xor(ps, 32);
  if (lane < 16) atomicAdd(&l[b * NSEQ + qt * 128 + w * 16 + lane], ps);
}

// ---------------- PV kernel: O[128, 128] = P[128, KL] @ vT^T, /l, -> concat ------
// qt chosen via balanced permutation: each CU's 4 co-resident blocks (groups
// {g, g+8, g+16, g+24}) have constant KL-sum (62*128), fixing the 1.5x per-CU
// imbalance of the naive heavy-first order.
__global__ __launch_bounds__(256, 4) void pv_kernel(
    const unsigned short* __restrict__ P, const unsigned short* __restrict__ vT,
    const float* __restrict__ l, unsigned short* __restrict__ concat) {
  __shared__ unsigned short LDSp[17408];  // As | Bs; epilogue reuses as [128][136]
  unsigned short* Asb = LDSp;
  unsigned short* Bsb = LDSp + 8192;
  const int tid = threadIdx.x;
  const int bid = blockIdx.x;
  const int g = bid >> 5;
  int qt;
  if (g < 8) qt = 31 - g;
  else if (g < 16) qt = 23 - g;
  else if (g < 24) qt = g;
  else qt = g - 24;
  const int rest = bid & 31;
  const int b = rest >> 3;
  const int nt = rest & 7;
  const int KL = (qt + 1) * 128;
  const unsigned short* A =
      P + (size_t)b * P_PER_B + (size_t)(qt * (qt + 1) / 2) * P_TILE;
  const unsigned short* Bt = vT + (size_t)b * DM * NSEQ;
  const int n0 = nt * 128;
  const int lane = tid & 63;
  const int w = tid >> 6;
  const int lr = lane & 15;
  const int lg = lane >> 4;
  const int wr = (w >> 1) * 64;
  const int wc = (w & 1) * 64;
  const int rSwz = (lr & 7) << 3;

  f32x4 acc[4][4];
#pragma unroll
  for (int i = 0; i < 4; i++)
#pragma unroll
    for (int j = 0; j < 4; j++)
#pragma unroll
      for (int r = 0; r < 4; r++) acc[i][j][r] = 0.0f;

  for (int k0 = 0; k0 < KL; k0 += 64) {
#pragma unroll
    for (int j = 0; j < 4; j++) {
      const int boff = w * 4096 + j * 1024 + lane * 16;
      const int row = boff >> 7;
      const int col = (((boff & 127) >> 1)) ^ ((row & 7) << 3);
      gload_lds16(A + (size_t)row * KL + k0 + col,
                  Asb + (boff - lane * 16) / 2);
    }
#pragma unroll
    for (int j = 0; j < 4; j++) {
      const int boff = w * 4096 + j * 1024 + lane * 16;
      const int row = boff >> 7;
      const int col = (((boff & 127) >> 1)) ^ ((row & 7) << 3);
      gload_lds16(Bt + (size_t)(n0 + row) * NSEQ + k0 + col,
                  Bsb + (boff - lane * 16) / 2);
    }
    __syncthreads();
#pragma unroll
    for (int kk = 0; kk < 64; kk += 32) {
      bf16x8 af[4], bfr[4];
#pragma unroll
      for (int i = 0; i < 4; i++)
        af[i] = *reinterpret_cast<const bf16x8*>(
            Asb + (wr + i * 16 + lr) * 64 + ((kk + lg * 8) ^ rSwz));
#pragma unroll
      for (int j = 0; j < 4; j++)
        bfr[j] = *reinterpret_cast<const bf16x8*>(
            Bsb + (wc + j * 16 + lr) * 64 + ((kk + lg * 8) ^ rSwz));
#pragma unroll
      for (int i = 0; i < 4; i++)
#pragma unroll
        for (int j = 0; j < 4; j++)
          acc[i][j] = __builtin_amdgcn_mfma_f32_16x16x32_bf16(af[i], bfr[j],
                                                              acc[i][j], 0, 0, 0);
    }
    __syncthreads();
  }

  const float* lb = l + b * NSEQ + qt * 128;
#pragma unroll
  for (int i = 0; i < 4; i++) {
    f32x4 lv = *reinterpret_cast<const f32x4*>(&lb[wr + i * 16 + lg * 4]);
    f32x4 inv;
#pragma unroll
    for (int r = 0; r < 4; r++) inv[r] = 1.0f / lv[r];
#pragma unroll
    for (int j = 0; j < 4; j++)
#pragma unroll
      for (int r = 0; r < 4; r++)
        LDSp[(wr + i * 16 + lg * 4 + r) * 136 + wc + j * 16 + lr] =
            f2bf(acc[i][j][r] * inv[r]);
  }
  __syncthreads();
#pragma unroll
  for (int it = 0; it < 8; ++it) {
    const int chunk = tid + it * 256;  // 2048 chunks = 128 rows x 16
    const int row = chunk >> 4, cc = chunk & 15;
    *reinterpret_cast<u16x8*>(concat +
                              (size_t)(b * NSEQ + qt * 128 + row) * 2048 + 1024 +
                              n0 + cc * 8) =
        *reinterpret_cast<const u16x8*>(&LDSp[row * 136 + cc * 8]);
  }
}

extern "C" void kernel_launch(void* const* d_in, const int* in_sizes, int n_in,
                              void* d_out, int out_size, void* d_ws,
                              size_t ws_size, hipStream_t stream) {
  (void)in_sizes;
  (void)n_in;
  (void)out_size;
  const float* x = (const float*)d_in[0];
  const float* expand = (const float*)d_in[1];
  const float* project = (const float*)d_in[2];
  const float* pbm = (const float*)d_in[3];
  float* out = (float*)d_out;

  // Region map:
  // [0, 8.4)       qk [16384][256]
  // [8.4, 41.9)    vT [4][1024][4096]   (written by gate GEMM epilogue)
  // [41.9, 111.2)  P (causal-packed)
  // [111.2,+64K)   l
  // [111.3, 120.2) expandT' (permuted, 4352x1024)
  // [142.6, 209.7) concat
  // [209.7, 243.3) nx  (projectT aliases after fused GEMM consumes nx)
  const size_t QK_BYTES = (size_t)16384 * 256 * 2;
  const size_t VT_BYTES = (size_t)16384 * 1024 * 2;
  const size_t P_BYTES = (size_t)NBATCH * P_PER_B * 2;
  const size_t L_BYTES = (size_t)NBATCH * NSEQ * 4;
  const size_t GH_BYTES = (size_t)16384 * 4096 * 2;
  const size_t CAT_BYTES = (size_t)16384 * 2048 * 2;
  const size_t NX_BYTES = (size_t)16384 * DM * 2;
  if (ws_size < QK_BYTES + GH_BYTES + CAT_BYTES + NX_BYTES) return;

  char* ws = (char*)d_ws;
  unsigned short* qk = (unsigned short*)ws;
  unsigned short* vT = (unsigned short*)(ws + QK_BYTES);
  unsigned short* P = (unsigned short*)(ws + QK_BYTES + VT_BYTES);
  float* l = (float*)(ws + QK_BYTES + VT_BYTES + P_BYTES);
  unsigned short* expandT =
      (unsigned short*)(ws + QK_BYTES + VT_BYTES + P_BYTES + L_BYTES);
  unsigned short* concat = (unsigned short*)(ws + QK_BYTES + GH_BYTES);
  unsigned short* nx = (unsigned short*)(ws + QK_BYTES + GH_BYTES + CAT_BYTES);
  unsigned short* projectT = nx;

  // 0a. expandT'[perm(n)][k] = bf16(expand[k][n])
  tconv_kernel<true><<<dim3(68, 16), 256, 0, stream>>>(expand, expandT, 1024, 4352);
  // 1. LayerNorm
  ln_kernel<<<16384, 256, 0, stream>>>(x, nx);
  // 2. fused expand GEMM (grid 1088): qk + local->concat + v->vT
  gemm256_kernel<2><<<dim3(1088), 512, 0, stream>>>(
      nx, DM, expandT, DM, (void*)concat, (void*)vT, (void*)qk, 0, DM, 17,
      nullptr);
  // 3. P = softmax numerator; l zeroed first
  hipMemsetAsync(l, 0, L_BYTES, stream);
  pk_kernel<<<dim3(NBATCH * 528), 512, 0, stream>>>(qk, pbm, P, l);
  // 4. attn = (P @ V) / l -> concat[:, 1024:2048]
  pv_kernel<<<dim3(1024), 256, 0, stream>>>(P, vT, l, concat);
  // 5. projectT (nx dead after step 2)
  tconv_kernel<false><<<dim3(16, 32), 256, 0, stream>>>(project, projectT, 2048, DM);
  // 6. out = x + concat @ projectT^T
  gemm256_kernel<1><<<dim3(64 * 4), 512, 0, stream>>>(
      concat, 2048, projectT, 2048, (void*)out, nullptr, nullptr, DM, 2048, 4, x);
}